// Round 1
// baseline (2695.951 us; speedup 1.0000x reference)
//
#include <hip/hip_runtime.h>
#include <cfloat>
#include <cstdint>

// MahalanobisKnnModule: top-5 Mahalanobis neighbors -> label histogram.
// Pipeline (all on `stream`):
//   1) zt_kernel:     ZT[256][2048] = M @ X_eval^T          (0.27 GF)
//   2) xprod_kernel:  Xprod[i] = x_i^T M x_i                (13.1 GF)
//   3) cross_topk:    fused X_train@ZT GEMM + per-column running top-5
//                     per (2048-row chunk x 128-col tile); Y_prod dropped
//                     (constant per column -> rank-invariant). (105 GF)
//   4) finalize:      merge 49 chunk top-5s per eval point, histogram.
// ws layout (floats): ZT | Xprod | cand_v | cand_i  (~6.5 MB total)

#define DD   256
#define NLAB 100
#define KNN  5
#define COLS 128
#define CHUNK 2048
#define RT   64
#define KS   64

typedef float4 f4;

__device__ __forceinline__ void gload_lds16(const float* g, float* l) {
  __builtin_amdgcn_global_load_lds(
      (const __attribute__((address_space(1))) void*)g,
      (__attribute__((address_space(3))) void*)l,
      16, 0, 0);
}

__device__ __forceinline__ bool lex_lt(float v, int id, float rv, int rid) {
  return (v < rv) || (v == rv && id < rid);
}

// static-index sorted-5 insert (no runtime register indexing -> no scratch)
__device__ __forceinline__ void ins5(float (&bv)[KNN], int (&bi)[KNN], float v, int id) {
  if (!lex_lt(v, id, bv[4], bi[4])) return;
  if (lex_lt(v, id, bv[3], bi[3])) {
    bv[4] = bv[3]; bi[4] = bi[3];
    if (lex_lt(v, id, bv[2], bi[2])) {
      bv[3] = bv[2]; bi[3] = bi[2];
      if (lex_lt(v, id, bv[1], bi[1])) {
        bv[2] = bv[1]; bi[2] = bi[1];
        if (lex_lt(v, id, bv[0], bi[0])) {
          bv[1] = bv[0]; bi[1] = bi[0]; bv[0] = v; bi[0] = id;
        } else { bv[1] = v; bi[1] = id; }
      } else { bv[2] = v; bi[2] = id; }
    } else { bv[3] = v; bi[3] = id; }
  } else { bv[4] = v; bi[4] = id; }
}

// ---------------- kernel 1: ZT = M @ X_eval^T  [256][NEVAL] ----------------
__global__ __launch_bounds__(256)
void zt_kernel(const float* __restrict__ M, const float* __restrict__ Xe,
               float* __restrict__ ZT, int NEVAL) {
  __shared__ float xe_lds[64 * 257];          // [j][k], pad->conflict-free
  const int t = threadIdx.x;
  const int j0 = blockIdx.x * 64;
  const int dbase = blockIdx.y * 64 + (t >> 6) * 16;
#pragma unroll
  for (int it = 0; it < 16; ++it) {
    int id = t + it * 256;                    // [0,4096)
    int r = id >> 6, k4 = id & 63;
    f4 v = *(const f4*)(Xe + (size_t)(j0 + r) * DD + 4 * k4);
    float* p = &xe_lds[r * 257 + 4 * k4];
    p[0] = v.x; p[1] = v.y; p[2] = v.z; p[3] = v.w;
  }
  __syncthreads();
  const int j = t & 63;
  float acc[16];
#pragma unroll
  for (int dd = 0; dd < 16; ++dd) acc[dd] = 0.f;
  for (int k4 = 0; k4 < 64; ++k4) {
    const float* xp = &xe_lds[j * 257 + 4 * k4];
    float x0 = xp[0], x1 = xp[1], x2 = xp[2], x3 = xp[3];
#pragma unroll
    for (int dd = 0; dd < 16; ++dd) {
      f4 m = *(const f4*)(M + (size_t)(dbase + dd) * DD + 4 * k4);
      acc[dd] = fmaf(m.x, x0, fmaf(m.y, x1, fmaf(m.z, x2, fmaf(m.w, x3, acc[dd]))));
    }
  }
#pragma unroll
  for (int dd = 0; dd < 16; ++dd)
    ZT[(size_t)(dbase + dd) * NEVAL + j0 + j] = acc[dd];
}

// ---------------- kernel 2: Xprod[i] = x_i^T M x_i ----------------
__global__ __launch_bounds__(256)
void xprod_kernel(const float* __restrict__ X, const float* __restrict__ M,
                  float* __restrict__ Xprod, int NT) {
  __shared__ float x_lds[64 * 257];
  __shared__ float red[4][64];
  const int t = threadIdx.x;
  const int row0 = blockIdx.x * 64;
#pragma unroll
  for (int it = 0; it < 16; ++it) {
    int id = t + it * 256;
    int r = id >> 6, k4 = id & 63;
    int grow = row0 + r; if (grow >= NT) grow = NT - 1;
    f4 v = *(const f4*)(X + (size_t)grow * DD + 4 * k4);
    float* p = &x_lds[r * 257 + 4 * k4];
    p[0] = v.x; p[1] = v.y; p[2] = v.z; p[3] = v.w;
  }
  __syncthreads();
  const int r = t & 63, part = t >> 6;
  float acc = 0.f;
  for (int db = 0; db < 8; ++db) {
    const int d0 = part * 64 + db * 8;
    float macc[8];
#pragma unroll
    for (int dd = 0; dd < 8; ++dd) macc[dd] = 0.f;
    for (int k4 = 0; k4 < 64; ++k4) {
      const float* xp = &x_lds[r * 257 + 4 * k4];
      float x0 = xp[0], x1 = xp[1], x2 = xp[2], x3 = xp[3];
#pragma unroll
      for (int dd = 0; dd < 8; ++dd) {
        f4 m = *(const f4*)(M + (size_t)(d0 + dd) * DD + 4 * k4);
        macc[dd] = fmaf(m.x, x0, fmaf(m.y, x1, fmaf(m.z, x2, fmaf(m.w, x3, macc[dd]))));
      }
    }
#pragma unroll
    for (int dd = 0; dd < 8; ++dd)
      acc = fmaf(x_lds[r * 257 + d0 + dd], macc[dd], acc);
  }
  red[part][r] = acc;
  __syncthreads();
  if (t < 64) {
    int grow = row0 + t;
    if (grow < NT)
      Xprod[grow] = red[0][t] + red[1][t] + red[2][t] + red[3][t];
  }
}

// ------- kernel 3: fused cross GEMM + per-column top-5 per chunk -------
__global__ __launch_bounds__(256)
void cross_topk_kernel(const float* __restrict__ X, const float* __restrict__ ZT,
                       const float* __restrict__ Xprod,
                       float* __restrict__ cand_v, int* __restrict__ cand_i,
                       int NT, int NEVAL) {
  __shared__ float A_lds[RT * KS];     // [r][k] 16 KB (also reused: merge vals)
  __shared__ float B_lds[KS * COLS];   // [k][c] 32 KB; reused as S[r][c], merge idx
  __shared__ float xp_lds[RT];

  const int t = threadIdx.x;
  const int w = t >> 6, lane = t & 63;
  const int tc = t & 31, tr = t >> 5;     // GEMM map: 8 rows x 4 cols/thread
  const int sc = t & 127, rh = t >> 7;    // scan map: col sc, row-half rh
  const int c0 = blockIdx.x * COLS;
  const int ch = blockIdx.y;
  const int row0 = ch * CHUNK;
  const int rows = min(CHUNK, NT - row0);
  const int ntile = (rows + RT - 1) / RT;

  float bv[KNN]; int bi[KNN];
#pragma unroll
  for (int s = 0; s < KNN; ++s) { bv[s] = FLT_MAX; bi[s] = 0x7fffffff; }

  for (int rt = 0; rt < ntile; ++rt) {
    const int trow0 = row0 + rt * RT;
    float acc[8][4];
#pragma unroll
    for (int i = 0; i < 8; ++i)
#pragma unroll
      for (int j = 0; j < 4; ++j) acc[i][j] = 0.f;

    for (int k0 = 0; k0 < DD; k0 += KS) {
      // stage A tile [64 rows][64 k] (linear LDS, per-wave uniform base)
#pragma unroll
      for (int i = 0; i < 4; ++i) {
        int f = (w * 4 + i) * 64 + lane;          // f4 index in [0,1024)
        int r = f >> 4, k4 = f & 15;
        int grow = trow0 + r; if (grow >= NT) grow = NT - 1;
        gload_lds16(X + (size_t)grow * DD + k0 + 4 * k4,
                    A_lds + (w * 4 + i) * 256);
      }
      // stage B tile ZT[k0..+63][c0..+127]
#pragma unroll
      for (int i = 0; i < 8; ++i) {
        int f = (w * 8 + i) * 64 + lane;          // f4 index in [0,2048)
        int kr = f >> 5, c4 = f & 31;
        gload_lds16(ZT + (size_t)(k0 + kr) * NEVAL + c0 + 4 * c4,
                    B_lds + (w * 8 + i) * 256);
      }
      if (k0 == 0 && t < RT) {
        int grow = trow0 + t; if (grow >= NT) grow = NT - 1;
        xp_lds[t] = Xprod[grow];
      }
      __syncthreads();
#pragma unroll 4
      for (int k = 0; k < KS; ++k) {
        float a[8], b[4];
#pragma unroll
        for (int i = 0; i < 8; ++i) a[i] = A_lds[(tr * 8 + i) * KS + k];
#pragma unroll
        for (int j = 0; j < 4; ++j) b[j] = B_lds[k * COLS + tc + 32 * j];
#pragma unroll
        for (int i = 0; i < 8; ++i)
#pragma unroll
          for (int j = 0; j < 4; ++j)
            acc[i][j] = fmaf(a[i], b[j], acc[i][j]);
      }
      __syncthreads();
    }
    // dump score tile S into B_lds (B consumed; restaged next tile)
#pragma unroll
    for (int i = 0; i < 8; ++i)
#pragma unroll
      for (int j = 0; j < 4; ++j)
        B_lds[(tr * 8 + i) * COLS + tc + 32 * j] = acc[i][j];
    __syncthreads();
    // scan: thread owns column sc, rows rh*32..rh*32+31 (ascending ids)
#pragma unroll 4
    for (int rr = 0; rr < 32; ++rr) {
      int r = rh * 32 + rr;
      int grow = trow0 + r;
      if (grow < NT) {
        float v = fmaf(-2.0f, B_lds[r * COLS + sc], xp_lds[r]);
        if (v < bv[4]) {            // strict < keeps earliest id (stable)
          if (v < bv[3]) {
            bv[4] = bv[3]; bi[4] = bi[3];
            if (v < bv[2]) {
              bv[3] = bv[2]; bi[3] = bi[2];
              if (v < bv[1]) {
                bv[2] = bv[1]; bi[2] = bi[1];
                if (v < bv[0]) {
                  bv[1] = bv[0]; bi[1] = bi[0]; bv[0] = v; bi[0] = grow;
                } else { bv[1] = v; bi[1] = grow; }
              } else { bv[2] = v; bi[2] = grow; }
            } else { bv[3] = v; bi[3] = grow; }
          } else { bv[4] = v; bi[4] = grow; }
        }
      }
    }
    __syncthreads();
  }

  // merge the two row-half lists per column (alias A_lds/B_lds for staging)
  float* mg_v = A_lds;           // [COLS][KNN]
  int*   mg_i = (int*)B_lds;     // [COLS][KNN]
  if (rh == 1) {
#pragma unroll
    for (int s = 0; s < KNN; ++s) {
      mg_v[sc * KNN + s] = bv[s];
      mg_i[sc * KNN + s] = bi[s];
    }
  }
  __syncthreads();
  if (rh == 0) {
#pragma unroll
    for (int s = 0; s < KNN; ++s)
      ins5(bv, bi, mg_v[sc * KNN + s], mg_i[sc * KNN + s]);
    size_t base = ((size_t)ch * NEVAL + c0 + sc) * KNN;
#pragma unroll
    for (int s = 0; s < KNN; ++s) { cand_v[base + s] = bv[s]; cand_i[base + s] = bi[s]; }
  }
}

// ---------------- kernel 4: merge chunks, histogram labels ----------------
__global__ __launch_bounds__(64)
void finalize_kernel(const float* __restrict__ cand_v, const int* __restrict__ cand_i,
                     const int* __restrict__ y, float* __restrict__ out,
                     int NCH, int NEVAL) {
  const int j = blockIdx.x;
  const int lane = threadIdx.x;
  float bv[KNN]; int bi[KNN];
#pragma unroll
  for (int s = 0; s < KNN; ++s) { bv[s] = FLT_MAX; bi[s] = 0x7fffffff; }
  const int NC = NCH * KNN;     // 245 candidates
  for (int q = lane; q < NC; q += 64) {
    int chq = q / KNN, s = q - chq * KNN;
    size_t o = ((size_t)chq * NEVAL + j) * KNN + s;
    ins5(bv, bi, cand_v[o], cand_i[o]);
  }
#pragma unroll
  for (int off = 32; off >= 1; off >>= 1) {
    float pv[KNN]; int pi[KNN];
#pragma unroll
    for (int s = 0; s < KNN; ++s) {
      pv[s] = __shfl_down(bv[s], off);
      pi[s] = __shfl_down(bi[s], off);
    }
#pragma unroll
    for (int s = 0; s < KNN; ++s) ins5(bv, bi, pv[s], pi[s]);
  }
  int lb[KNN];
  if (lane == 0) {
#pragma unroll
    for (int s = 0; s < KNN; ++s) lb[s] = y[bi[s]];
  }
#pragma unroll
  for (int s = 0; s < KNN; ++s) lb[s] = __shfl(lb[s], 0);
  for (int q = lane; q < NLAB; q += 64) {
    int cnt = (lb[0] == q) + (lb[1] == q) + (lb[2] == q) + (lb[3] == q) + (lb[4] == q);
    out[(size_t)j * NLAB + q] = (float)cnt - (float)q * 0.01f;
  }
}

extern "C" void kernel_launch(void* const* d_in, const int* in_sizes, int n_in,
                              void* d_out, int out_size, void* d_ws, size_t ws_size,
                              hipStream_t stream) {
  const float* X  = (const float*)d_in[0];
  const float* M  = (const float*)d_in[1];
  const float* Xe = (const float*)d_in[2];
  const int*   y  = (const int*)d_in[3];
  const int NT    = in_sizes[0] / DD;     // 100000
  const int NEVAL = in_sizes[2] / DD;     // 2048
  const int NCH   = (NT + CHUNK - 1) / CHUNK;  // 49

  float* ws     = (float*)d_ws;
  float* ZT     = ws;                                  // DD*NEVAL
  float* Xprod  = ZT + (size_t)DD * NEVAL;             // NT
  float* cand_v = Xprod + NT;                          // NCH*NEVAL*KNN
  int*   cand_i = (int*)(cand_v + (size_t)NCH * NEVAL * KNN);
  float* out    = (float*)d_out;

  zt_kernel<<<dim3(NEVAL / 64, DD / 64), 256, 0, stream>>>(M, Xe, ZT, NEVAL);
  xprod_kernel<<<dim3((NT + 63) / 64), 256, 0, stream>>>(X, M, Xprod, NT);
  cross_topk_kernel<<<dim3(NEVAL / COLS, NCH), 256, 0, stream>>>(
      X, ZT, Xprod, cand_v, cand_i, NT, NEVAL);
  finalize_kernel<<<dim3(NEVAL), 64, 0, stream>>>(cand_v, cand_i, y, out, NCH, NEVAL);
}

// Round 2
// 1413.900 us; speedup vs baseline: 1.9067x; 1.9067x over previous
//
#include <hip/hip_runtime.h>
#include <cfloat>
#include <cstdint>

// MahalanobisKnnModule v2: bf16 split-precision MFMA cross GEMM.
//   prep:    ZTf32[256][2048] = M@Xe^T  (f32, for exact rescore)
//            Z2hi/Z2lo = hi/lo bf16 split of -2*ZT^T, pre-arranged in the
//            exact swizzled-slot order the cross kernel's global_load_lds
//            staging consumes (XOR ^((row&7)<<4) bank swizzle baked in).
//   xprod:   Xprod[i] = x_i^T M x_i (f32 exact)
//   cross:   S = Xprod[i] + sum_k X[i,k]*Z2[j,k] via 3x mfma_16x16x32_bf16
//            (hh+hl+lh), per-column running top-5 in registers -> 4 partial
//            lists per (chunk, column).
//   final:   merge 49*4*5=980 approx candidates -> top-10 -> exact f32
//            rescore (Xprod - 2*x.ztcol) -> top-5 -> label histogram.

#define DD    256
#define NLAB  100
#define KNN   5
#define COLS  128
#define RT    64
#define KS    64
#define CHUNK 2048
#define NSRC  4

typedef float4 f4;
typedef __attribute__((ext_vector_type(8))) short bfrag;   // 8 bf16
typedef __attribute__((ext_vector_type(4))) float f32x4;

__device__ __forceinline__ void gload_lds16(const void* g, void* l) {
  __builtin_amdgcn_global_load_lds(
      (const __attribute__((address_space(1))) void*)g,
      (__attribute__((address_space(3))) void*)l, 16, 0, 0);
}

// round-to-nearest hi (8-bit mantissa), truncated lo of the residual
__device__ __forceinline__ void split2(float v, uint32_t& h, uint32_t& l) {
  uint32_t b = __float_as_uint(v);
  uint32_t hb = (b + 0x8000u) & 0xffff0000u;
  float lf = v - __uint_as_float(hb);
  h = hb >> 16;
  l = __float_as_uint(lf) >> 16;
}

__device__ __forceinline__ bool lex_lt(float v, int id, float rv, int rid) {
  return (v < rv) || (v == rv && id < rid);
}

__device__ __forceinline__ void ins5lex(float (&bv)[KNN], int (&bi)[KNN], float v, int id) {
  if (!lex_lt(v, id, bv[4], bi[4])) return;
  if (lex_lt(v, id, bv[3], bi[3])) {
    bv[4] = bv[3]; bi[4] = bi[3];
    if (lex_lt(v, id, bv[2], bi[2])) {
      bv[3] = bv[2]; bi[3] = bi[2];
      if (lex_lt(v, id, bv[1], bi[1])) {
        bv[2] = bv[1]; bi[2] = bi[1];
        if (lex_lt(v, id, bv[0], bi[0])) {
          bv[1] = bv[0]; bi[1] = bi[0]; bv[0] = v; bi[0] = id;
        } else { bv[1] = v; bi[1] = id; }
      } else { bv[2] = v; bi[2] = id; }
    } else { bv[3] = v; bi[3] = id; }
  } else { bv[4] = v; bi[4] = id; }
}

__device__ __forceinline__ void ins10(float (&bv)[10], int (&bi)[10], float v, int id) {
  if (!lex_lt(v, id, bv[9], bi[9])) return;
  bool placed = false;
#pragma unroll
  for (int s = 9; s >= 1; --s) {
    if (!placed) {
      if (lex_lt(v, id, bv[s - 1], bi[s - 1])) { bv[s] = bv[s - 1]; bi[s] = bi[s - 1]; }
      else { bv[s] = v; bi[s] = id; placed = true; }
    }
  }
  if (!placed) { bv[0] = v; bi[0] = id; }
}

// ---------- prep: ZTf32 + arranged/swizzled bf16 split of -2*ZT^T ----------
__global__ __launch_bounds__(256)
void prep_kernel(const float* __restrict__ M, const float* __restrict__ Xe,
                 float* __restrict__ ZTf32, uint4* __restrict__ Z2h,
                 uint4* __restrict__ Z2l, int NEVAL) {
  __shared__ float xe_lds[64 * 257];
  const int t = threadIdx.x;
  const int j0 = blockIdx.x * 64;
  const int part = t >> 6;
  const int dbase = blockIdx.y * 64 + part * 16;
#pragma unroll
  for (int it = 0; it < 16; ++it) {
    int id = t + it * 256;
    int r = id >> 6, k4 = id & 63;
    f4 v = *(const f4*)(Xe + (size_t)(j0 + r) * DD + 4 * k4);
    float* p = &xe_lds[r * 257 + 4 * k4];
    p[0] = v.x; p[1] = v.y; p[2] = v.z; p[3] = v.w;
  }
  __syncthreads();
  const int j = t & 63;
  float acc[16];
#pragma unroll
  for (int dd = 0; dd < 16; ++dd) acc[dd] = 0.f;
  for (int k4 = 0; k4 < 64; ++k4) {
    const float* xp = &xe_lds[j * 257 + 4 * k4];
    float x0 = xp[0], x1 = xp[1], x2 = xp[2], x3 = xp[3];
#pragma unroll
    for (int dd = 0; dd < 16; ++dd) {
      f4 m = *(const f4*)(M + (size_t)(dbase + dd) * DD + 4 * k4);
      acc[dd] = fmaf(m.x, x0, fmaf(m.y, x1, fmaf(m.z, x2, fmaf(m.w, x3, acc[dd]))));
    }
  }
  const int jg = j0 + j;
#pragma unroll
  for (int dd = 0; dd < 16; ++dd)
    ZTf32[(size_t)(dbase + dd) * NEVAL + jg] = acc[dd];
  // arranged swizzled bf16 split of -2*acc
  const int cc = jg & 127, ct2 = jg >> 7;
  const int kit = dbase >> 6;            // == blockIdx.y
  const int sbase = (dbase & 63) >> 3;   // {0,2,4,6}
#pragma unroll
  for (int half = 0; half < 2; ++half) {
    int s = sbase + half;
    uint32_t hw[4], lw[4];
#pragma unroll
    for (int e = 0; e < 4; ++e) {
      uint32_t h0, l0, h1, l1;
      split2(-2.f * acc[half * 8 + 2 * e], h0, l0);
      split2(-2.f * acc[half * 8 + 2 * e + 1], h1, l1);
      hw[e] = h0 | (h1 << 16);
      lw[e] = l0 | (l1 << 16);
    }
    int pi = 8 * cc + (s ^ (cc & 7));
    size_t o = (size_t)(ct2 * 4 + kit) * 1024 + pi;
    Z2h[o] = make_uint4(hw[0], hw[1], hw[2], hw[3]);
    Z2l[o] = make_uint4(lw[0], lw[1], lw[2], lw[3]);
  }
}

// ---------------- xprod: Xprod[i] = x_i^T M x_i (unchanged) ----------------
__global__ __launch_bounds__(256)
void xprod_kernel(const float* __restrict__ X, const float* __restrict__ M,
                  float* __restrict__ Xprod, int NT) {
  __shared__ float x_lds[64 * 257];
  __shared__ float red[4][64];
  const int t = threadIdx.x;
  const int row0 = blockIdx.x * 64;
#pragma unroll
  for (int it = 0; it < 16; ++it) {
    int id = t + it * 256;
    int r = id >> 6, k4 = id & 63;
    int grow = row0 + r; if (grow >= NT) grow = NT - 1;
    f4 v = *(const f4*)(X + (size_t)grow * DD + 4 * k4);
    float* p = &x_lds[r * 257 + 4 * k4];
    p[0] = v.x; p[1] = v.y; p[2] = v.z; p[3] = v.w;
  }
  __syncthreads();
  const int r = t & 63, part = t >> 6;
  float acc = 0.f;
  for (int db = 0; db < 8; ++db) {
    const int d0 = part * 64 + db * 8;
    float macc[8];
#pragma unroll
    for (int dd = 0; dd < 8; ++dd) macc[dd] = 0.f;
    for (int k4 = 0; k4 < 64; ++k4) {
      const float* xp = &x_lds[r * 257 + 4 * k4];
      float x0 = xp[0], x1 = xp[1], x2 = xp[2], x3 = xp[3];
#pragma unroll
      for (int dd = 0; dd < 8; ++dd) {
        f4 m = *(const f4*)(M + (size_t)(d0 + dd) * DD + 4 * k4);
        macc[dd] = fmaf(m.x, x0, fmaf(m.y, x1, fmaf(m.z, x2, fmaf(m.w, x3, macc[dd]))));
      }
    }
#pragma unroll
    for (int dd = 0; dd < 8; ++dd)
      acc = fmaf(x_lds[r * 257 + d0 + dd], macc[dd], acc);
  }
  red[part][r] = acc;
  __syncthreads();
  if (t < 64) {
    int grow = row0 + t;
    if (grow < NT)
      Xprod[grow] = red[0][t] + red[1][t] + red[2][t] + red[3][t];
  }
}

// ------------- cross: MFMA GEMM + per-column running top-5 -------------
__global__ __launch_bounds__(256, 3)
void cross_topk_kernel(const float* __restrict__ X, const uint4* __restrict__ Z2h,
                       const uint4* __restrict__ Z2l, const float* __restrict__ Xprod,
                       float* __restrict__ cand_v, int* __restrict__ cand_i,
                       int NT, int NEVAL) {
  __shared__ short A_hi[RT * KS];      // 8 KB, swizzled rows of 128 B
  __shared__ short A_lo[RT * KS];
  __shared__ short B_hi[COLS * KS];    // 16 KB
  __shared__ short B_lo[COLS * KS];
  __shared__ float xp_lds[RT];

  const int t = threadIdx.x;
  const int w = t >> 6, lane = t & 63;
  const int l15 = lane & 15, l4 = lane >> 4;
  const int ct = blockIdx.x;           // col tile (128 cols)
  const int ch = blockIdx.y;
  const int c0 = ct * COLS;
  const int row0 = ch * CHUNK;
  const int rows = min(CHUNK, NT - row0);
  const int ntile = (rows + RT - 1) / RT;

  float bv[2][KNN]; int bi[2][KNN];
#pragma unroll
  for (int nf = 0; nf < 2; ++nf)
#pragma unroll
    for (int s = 0; s < KNN; ++s) { bv[nf][s] = FLT_MAX; bi[nf][s] = 0x7fffffff; }

  for (int rt = 0; rt < ntile; ++rt) {
    const int trow0 = row0 + rt * RT;
    if (t < RT) { int gr = trow0 + t; if (gr >= NT) gr = NT - 1; xp_lds[t] = Xprod[gr]; }
    f32x4 acc[4][2];
#pragma unroll
    for (int mf = 0; mf < 4; ++mf)
#pragma unroll
      for (int nf = 0; nf < 2; ++nf) { f32x4 z = {0.f, 0.f, 0.f, 0.f}; acc[mf][nf] = z; }

    for (int kit = 0; kit < 4; ++kit) {
      const int k0 = kit * KS;
      // stage A [64 rows][64 k] f32 -> hi/lo bf16, swizzled
#pragma unroll
      for (int i = 0; i < 4; ++i) {
        int f = t + 256 * i;               // f4 index in [0,1024)
        int r = f >> 4, k4 = f & 15;
        int grow = trow0 + r; if (grow >= NT) grow = NT - 1;
        f4 v = *(const f4*)(X + (size_t)grow * DD + k0 + 4 * k4);
        uint32_t h0, l0, h1, l1, h2, l2, h3, l3;
        split2(v.x, h0, l0); split2(v.y, h1, l1);
        split2(v.z, h2, l2); split2(v.w, h3, l3);
        int byte = (r * 128 + 8 * k4) ^ ((r & 7) << 4);
        *(uint2*)((char*)A_hi + byte) = make_uint2(h0 | (h1 << 16), h2 | (h3 << 16));
        *(uint2*)((char*)A_lo + byte) = make_uint2(l0 | (l1 << 16), l2 | (l3 << 16));
      }
      // stage B via pre-arranged global_load_lds (linear dest, swizzle baked in src)
      const uint4* srcH = Z2h + (size_t)(ct * 4 + kit) * 1024;
      const uint4* srcL = Z2l + (size_t)(ct * 4 + kit) * 1024;
#pragma unroll
      for (int i = 0; i < 4; ++i) {
        int sl = i * 256 + w * 64;
        gload_lds16(srcH + sl + lane, (char*)B_hi + sl * 16);
        gload_lds16(srcL + sl + lane, (char*)B_lo + sl * 16);
      }
      __syncthreads();
#pragma unroll
      for (int ks = 0; ks < 2; ++ks) {
        bfrag ah[4], al[4], bh[2], bl[2];
#pragma unroll
        for (int mf = 0; mf < 4; ++mf) {
          int m = mf * 16 + l15;
          int byte = (m * 128 + ks * 64 + l4 * 16) ^ ((m & 7) << 4);
          ah[mf] = *(const bfrag*)((const char*)A_hi + byte);
          al[mf] = *(const bfrag*)((const char*)A_lo + byte);
        }
#pragma unroll
        for (int nf = 0; nf < 2; ++nf) {
          int n = w * 32 + nf * 16 + l15;
          int byte = (n * 128 + ks * 64 + l4 * 16) ^ ((n & 7) << 4);
          bh[nf] = *(const bfrag*)((const char*)B_hi + byte);
          bl[nf] = *(const bfrag*)((const char*)B_lo + byte);
        }
#pragma unroll
        for (int mf = 0; mf < 4; ++mf)
#pragma unroll
          for (int nf = 0; nf < 2; ++nf) {
            acc[mf][nf] = __builtin_amdgcn_mfma_f32_16x16x32_bf16(ah[mf], bh[nf], acc[mf][nf], 0, 0, 0);
            acc[mf][nf] = __builtin_amdgcn_mfma_f32_16x16x32_bf16(ah[mf], bl[nf], acc[mf][nf], 0, 0, 0);
            acc[mf][nf] = __builtin_amdgcn_mfma_f32_16x16x32_bf16(al[mf], bh[nf], acc[mf][nf], 0, 0, 0);
          }
      }
      __syncthreads();
    }
    // epilogue: score = xp[row] + acc ; insert into per-column lists
#pragma unroll
    for (int mf = 0; mf < 4; ++mf) {
#pragma unroll
      for (int rg = 0; rg < 4; ++rg) {
        int rl = mf * 16 + l4 * 4 + rg;
        int grow = trow0 + rl;
        float xp = xp_lds[rl];
        bool ok = grow < NT;
#pragma unroll
        for (int nf = 0; nf < 2; ++nf) {
          float v = xp + acc[mf][nf][rg];
          if (ok && v < bv[nf][4]) {
            if (v < bv[nf][3]) {
              bv[nf][4] = bv[nf][3]; bi[nf][4] = bi[nf][3];
              if (v < bv[nf][2]) {
                bv[nf][3] = bv[nf][2]; bi[nf][3] = bi[nf][2];
                if (v < bv[nf][1]) {
                  bv[nf][2] = bv[nf][1]; bi[nf][2] = bi[nf][1];
                  if (v < bv[nf][0]) {
                    bv[nf][1] = bv[nf][0]; bi[nf][1] = bi[nf][0];
                    bv[nf][0] = v; bi[nf][0] = grow;
                  } else { bv[nf][1] = v; bi[nf][1] = grow; }
                } else { bv[nf][2] = v; bi[nf][2] = grow; }
              } else { bv[nf][3] = v; bi[nf][3] = grow; }
            } else { bv[nf][4] = v; bi[nf][4] = grow; }
          }
        }
      }
    }
    __syncthreads();
  }
  // write 4 partial lists per column
#pragma unroll
  for (int nf = 0; nf < 2; ++nf) {
    int col = c0 + w * 32 + nf * 16 + l15;
    size_t o = (((size_t)ch * NEVAL + col) * NSRC + l4) * KNN;
#pragma unroll
    for (int s = 0; s < KNN; ++s) { cand_v[o + s] = bv[nf][s]; cand_i[o + s] = bi[nf][s]; }
  }
}

// ------------- finalize: merge 980 -> top-10 -> exact rescore -> top-5 -------------
__global__ __launch_bounds__(64)
void finalize_kernel(const float* __restrict__ cand_v, const int* __restrict__ cand_i,
                     const float* __restrict__ X, const float* __restrict__ ZTf32,
                     const float* __restrict__ Xprod, const int* __restrict__ y,
                     float* __restrict__ out, int NCH, int NEVAL, int NT) {
  __shared__ float ztl[DD];
  const int j = blockIdx.x;
  const int lane = threadIdx.x;
#pragma unroll
  for (int i = 0; i < 4; ++i) {
    int k = lane + 64 * i;
    ztl[k] = ZTf32[(size_t)k * NEVAL + j];
  }
  __syncthreads();

  float bv[10]; int bi[10];
#pragma unroll
  for (int s = 0; s < 10; ++s) { bv[s] = FLT_MAX; bi[s] = 0x7fffffff; }
  const int NC = NCH * NSRC * KNN;     // 980
  for (int p = lane; p < NC; p += 64) {
    int chq = p / 20, u = p - chq * 20;
    size_t o = ((size_t)chq * NEVAL + j) * 20 + u;
    ins10(bv, bi, cand_v[o], cand_i[o]);
  }
#pragma unroll
  for (int st = 0; st < 6; ++st) {
    float pv[10]; int pi[10];
#pragma unroll
    for (int s = 0; s < 10; ++s) {
      pv[s] = __shfl_xor(bv[s], 1 << st);
      pi[s] = __shfl_xor(bi[s], 1 << st);
    }
#pragma unroll
    for (int s = 0; s < 10; ++s) ins10(bv, bi, pv[s], pi[s]);
  }
  // exact rescore of the 10 (all lanes hold identical lists)
  float ex[10];
#pragma unroll
  for (int c = 0; c < 10; ++c) {
    int idx = bi[c];
    float part = 0.f;
#pragma unroll
    for (int i = 0; i < 4; ++i) {
      int k = lane + 64 * i;
      part = fmaf(X[(size_t)idx * DD + k], ztl[k], part);
    }
#pragma unroll
    for (int st = 0; st < 6; ++st) part += __shfl_xor(part, 1 << st);
    ex[c] = Xprod[idx] - 2.f * part;
  }
  float fv[KNN]; int fi[KNN];
#pragma unroll
  for (int s = 0; s < KNN; ++s) { fv[s] = FLT_MAX; fi[s] = 0x7fffffff; }
#pragma unroll
  for (int c = 0; c < 10; ++c) ins5lex(fv, fi, ex[c], bi[c]);
  int lb[KNN];
#pragma unroll
  for (int s = 0; s < KNN; ++s) lb[s] = y[fi[s]];
  for (int q = lane; q < NLAB; q += 64) {
    int cnt = (lb[0] == q) + (lb[1] == q) + (lb[2] == q) + (lb[3] == q) + (lb[4] == q);
    out[(size_t)j * NLAB + q] = (float)cnt - (float)q * 0.01f;
  }
}

extern "C" void kernel_launch(void* const* d_in, const int* in_sizes, int n_in,
                              void* d_out, int out_size, void* d_ws, size_t ws_size,
                              hipStream_t stream) {
  const float* X  = (const float*)d_in[0];
  const float* M  = (const float*)d_in[1];
  const float* Xe = (const float*)d_in[2];
  const int*   y  = (const int*)d_in[3];
  const int NT    = in_sizes[0] / DD;          // 100000
  const int NEVAL = in_sizes[2] / DD;          // 2048
  const int NCH   = (NT + CHUNK - 1) / CHUNK;  // 49

  // ws layout (16B-aligned blocks)
  char* ws = (char*)d_ws;
  uint4* Z2h    = (uint4*)ws;                              // 16*4*1024 uint4 = 1 MB
  uint4* Z2l    = (uint4*)(ws + (1 << 20));                // 1 MB
  float* ZTf32  = (float*)(ws + (2 << 20));                // 2 MB
  float* Xprod  = (float*)(ws + (4 << 20));                // 100352 floats
  float* cand_v = (float*)(ws + (4 << 20) + 100352 * 4);
  int*   cand_i = (int*)((char*)cand_v + (size_t)NCH * NEVAL * NSRC * KNN * 4);
  float* out    = (float*)d_out;

  prep_kernel<<<dim3(NEVAL / 64, DD / 64), 256, 0, stream>>>(M, Xe, ZTf32, Z2h, Z2l, NEVAL);
  xprod_kernel<<<dim3((NT + 63) / 64), 256, 0, stream>>>(X, M, Xprod, NT);
  cross_topk_kernel<<<dim3(NEVAL / COLS, NCH), 256, 0, stream>>>(
      X, Z2h, Z2l, Xprod, cand_v, cand_i, NT, NEVAL);
  finalize_kernel<<<dim3(NEVAL), 64, 0, stream>>>(
      cand_v, cand_i, X, ZTf32, Xprod, y, out, NCH, NEVAL, NT);
}

// Round 3
// 755.538 us; speedup vs baseline: 3.5683x; 1.8714x over previous
//
#include <hip/hip_runtime.h>
#include <cfloat>
#include <cstdint>

// MahalanobisKnnModule v3:
//   msplit:  MT3 = 3-way bf16 split (hi/mid/lo) of M[k][d], frag-arranged in
//            the exact slot order xprod's global_load_lds B-staging consumes.
//   prep:    ZTf32 = M@Xe^T (f32, exact rescore) + Z2h/Z2l bf16 2-split of
//            -2*ZT^T, pre-arranged+swizzled for cross's staging.
//   xprod:   Xprod[i] = x_i^T M x_i via 3-split MFMA (6 products: error
//            ~2^-27 rel, below f32 noise). C tile dumped to LDS; epilogue
//            row-dot with exact f32 X. 64 rows/block, 2 blocks/CU.
//   cross:   S = Xprod[i] - 2*x_i.z_j via 2-split MFMA (hh+hl+lh), running
//            per-column top-5 -> 4 partial lists. XCD-swizzled grid.
//   final:   merge 980 -> top-10 -> exact f32 rescore -> top-5 -> histogram.

#define DD    256
#define NLAB  100
#define KNN   5
#define COLS  128
#define RT    64
#define KS    64
#define CHUNK 2048
#define NSRC  4

typedef float4 f4;
typedef __attribute__((ext_vector_type(8))) short bfrag;   // 8 bf16
typedef __attribute__((ext_vector_type(4))) float f32x4;

__device__ __forceinline__ void gload_lds16(const void* g, void* l) {
  __builtin_amdgcn_global_load_lds(
      (const __attribute__((address_space(1))) void*)g,
      (__attribute__((address_space(3))) void*)l, 16, 0, 0);
}

// 2-split: round-to-nearest hi, residual lo
__device__ __forceinline__ void split2(float v, uint32_t& h, uint32_t& l) {
  uint32_t b = __float_as_uint(v);
  uint32_t hb = (b + 0x8000u) & 0xffff0000u;
  float lf = v - __uint_as_float(hb);
  h = hb >> 16;
  l = __float_as_uint(lf) >> 16;
}

// 3-split: v ~= h + m + l with missing mass ~2^-25 |v|
__device__ __forceinline__ void split3(float v, uint32_t& h, uint32_t& m, uint32_t& l) {
  uint32_t b = __float_as_uint(v);
  uint32_t hb = (b + 0x8000u) & 0xffff0000u;
  float r1 = v - __uint_as_float(hb);
  uint32_t b1 = __float_as_uint(r1);
  uint32_t mb = (b1 + 0x8000u) & 0xffff0000u;
  float r2 = r1 - __uint_as_float(mb);
  uint32_t lb = (__float_as_uint(r2) + 0x8000u) & 0xffff0000u;
  h = hb >> 16; m = mb >> 16; l = lb >> 16;
}

__device__ __forceinline__ bool lex_lt(float v, int id, float rv, int rid) {
  return (v < rv) || (v == rv && id < rid);
}

__device__ __forceinline__ void ins5lex(float (&bv)[KNN], int (&bi)[KNN], float v, int id) {
  if (!lex_lt(v, id, bv[4], bi[4])) return;
  if (lex_lt(v, id, bv[3], bi[3])) {
    bv[4] = bv[3]; bi[4] = bi[3];
    if (lex_lt(v, id, bv[2], bi[2])) {
      bv[3] = bv[2]; bi[3] = bi[2];
      if (lex_lt(v, id, bv[1], bi[1])) {
        bv[2] = bv[1]; bi[2] = bi[1];
        if (lex_lt(v, id, bv[0], bi[0])) {
          bv[1] = bv[0]; bi[1] = bi[0]; bv[0] = v; bi[0] = id;
        } else { bv[1] = v; bi[1] = id; }
      } else { bv[2] = v; bi[2] = id; }
    } else { bv[3] = v; bi[3] = id; }
  } else { bv[4] = v; bi[4] = id; }
}

__device__ __forceinline__ void ins10(float (&bv)[10], int (&bi)[10], float v, int id) {
  if (!lex_lt(v, id, bv[9], bi[9])) return;
  bool placed = false;
#pragma unroll
  for (int s = 9; s >= 1; --s) {
    if (!placed) {
      if (lex_lt(v, id, bv[s - 1], bi[s - 1])) { bv[s] = bv[s - 1]; bi[s] = bi[s - 1]; }
      else { bv[s] = v; bi[s] = id; placed = true; }
    }
  }
  if (!placed) { bv[0] = v; bi[0] = id; }
}

// ---------- msplit: MT3[kit][nf][s][lane] = 3-split of M[k][d], frag-order ----------
__global__ __launch_bounds__(256)
void msplit_kernel(const float* __restrict__ M, uint4* __restrict__ MT3) {
  int id = blockIdx.x * 256 + threadIdx.x;   // [0, 8192)
  int lane = id & 63;
  int nf = (id >> 6) & 15;
  int kit = id >> 10;                        // [0,8)
  int d = nf * 16 + (lane & 15);
  int kb = kit * 32 + (lane >> 4) * 8;
  uint32_t hw[4], mw[4], lw[4];
#pragma unroll
  for (int e = 0; e < 4; ++e) {
    uint32_t h0, m0, l0, h1, m1, l1;
    split3(M[(size_t)(kb + 2 * e) * DD + d], h0, m0, l0);
    split3(M[(size_t)(kb + 2 * e + 1) * DD + d], h1, m1, l1);
    hw[e] = h0 | (h1 << 16); mw[e] = m0 | (m1 << 16); lw[e] = l0 | (l1 << 16);
  }
  size_t base = (size_t)(kit * 16 + nf) * 3 * 64;
  MT3[base + lane]       = make_uint4(hw[0], hw[1], hw[2], hw[3]);
  MT3[base + 64 + lane]  = make_uint4(mw[0], mw[1], mw[2], mw[3]);
  MT3[base + 128 + lane] = make_uint4(lw[0], lw[1], lw[2], lw[3]);
}

// ---------- prep: ZTf32 + arranged/swizzled bf16 2-split of -2*ZT^T ----------
__global__ __launch_bounds__(256)
void prep_kernel(const float* __restrict__ M, const float* __restrict__ Xe,
                 float* __restrict__ ZTf32, uint4* __restrict__ Z2h,
                 uint4* __restrict__ Z2l, int NEVAL) {
  __shared__ float xe_lds[64 * 257];
  const int t = threadIdx.x;
  const int j0 = blockIdx.x * 64;
  const int part = t >> 6;
  const int dbase = blockIdx.y * 64 + part * 16;
#pragma unroll
  for (int it = 0; it < 16; ++it) {
    int id = t + it * 256;
    int r = id >> 6, k4 = id & 63;
    f4 v = *(const f4*)(Xe + (size_t)(j0 + r) * DD + 4 * k4);
    float* p = &xe_lds[r * 257 + 4 * k4];
    p[0] = v.x; p[1] = v.y; p[2] = v.z; p[3] = v.w;
  }
  __syncthreads();
  const int j = t & 63;
  float acc[16];
#pragma unroll
  for (int dd = 0; dd < 16; ++dd) acc[dd] = 0.f;
  for (int k4 = 0; k4 < 64; ++k4) {
    const float* xp = &xe_lds[j * 257 + 4 * k4];
    float x0 = xp[0], x1 = xp[1], x2 = xp[2], x3 = xp[3];
#pragma unroll
    for (int dd = 0; dd < 16; ++dd) {
      f4 m = *(const f4*)(M + (size_t)(dbase + dd) * DD + 4 * k4);
      acc[dd] = fmaf(m.x, x0, fmaf(m.y, x1, fmaf(m.z, x2, fmaf(m.w, x3, acc[dd]))));
    }
  }
  const int jg = j0 + j;
#pragma unroll
  for (int dd = 0; dd < 16; ++dd)
    ZTf32[(size_t)(dbase + dd) * NEVAL + jg] = acc[dd];
  const int cc = jg & 127, ct2 = jg >> 7;
  const int kit = dbase >> 6;
  const int sbase = (dbase & 63) >> 3;
#pragma unroll
  for (int half = 0; half < 2; ++half) {
    int s = sbase + half;
    uint32_t hw[4], lw[4];
#pragma unroll
    for (int e = 0; e < 4; ++e) {
      uint32_t h0, l0, h1, l1;
      split2(-2.f * acc[half * 8 + 2 * e], h0, l0);
      split2(-2.f * acc[half * 8 + 2 * e + 1], h1, l1);
      hw[e] = h0 | (h1 << 16);
      lw[e] = l0 | (l1 << 16);
    }
    int pi = 8 * cc + (s ^ (cc & 7));
    size_t o = (size_t)(ct2 * 4 + kit) * 1024 + pi;
    Z2h[o] = make_uint4(hw[0], hw[1], hw[2], hw[3]);
    Z2l[o] = make_uint4(lw[0], lw[1], lw[2], lw[3]);
  }
}

// ---------- xprod v3: 3-split MFMA GEMM + fused row-dot ----------
__global__ __launch_bounds__(256, 2)
void xprod_kernel(const float* __restrict__ X, const uint4* __restrict__ MT3,
                  float* __restrict__ Xprod, int NT) {
  __shared__ __align__(16) char pool[66560];
  short* A3 = (short*)pool;                  // [4 w][3 s][64 lanes] x 16B = 12 KB
  char*  B3 = pool + 12288;                  // [16 nf][3 s][64 lanes] x 16B = 48 KB
  float* C  = (float*)pool;                  // [64][260] f32 overlay (post-barrier)

  const int t = threadIdx.x;
  const int w = t >> 6, lane = t & 63;
  const int l15 = lane & 15, l4 = lane >> 4;
  const int row0 = blockIdx.x * 64;
  const int r = t >> 2, g = t & 3;           // staging/epilogue map
  int grow = row0 + r; if (grow >= NT) grow = NT - 1;
  const float* xrow = X + (size_t)grow * DD;

  f32x4 acc[16];
#pragma unroll
  for (int nf = 0; nf < 16; ++nf) { f32x4 z = {0.f, 0.f, 0.f, 0.f}; acc[nf] = z; }

  for (int kit = 0; kit < 8; ++kit) {
    // stage A: thread covers (row r, k-octet g) -> one 16B slot per split
    f4 v0 = *(const f4*)(xrow + kit * 32 + g * 8);
    f4 v1 = *(const f4*)(xrow + kit * 32 + g * 8 + 4);
    uint32_t h[8], m[8], l[8];
    split3(v0.x, h[0], m[0], l[0]); split3(v0.y, h[1], m[1], l[1]);
    split3(v0.z, h[2], m[2], l[2]); split3(v0.w, h[3], m[3], l[3]);
    split3(v1.x, h[4], m[4], l[4]); split3(v1.y, h[5], m[5], l[5]);
    split3(v1.z, h[6], m[6], l[6]); split3(v1.w, h[7], m[7], l[7]);
    int slot = (r & 15) + 16 * g;
    int wb = r >> 4;
    *(uint4*)((char*)A3 + ((wb * 3 + 0) * 64 + slot) * 16) =
        make_uint4(h[0] | (h[1] << 16), h[2] | (h[3] << 16), h[4] | (h[5] << 16), h[6] | (h[7] << 16));
    *(uint4*)((char*)A3 + ((wb * 3 + 1) * 64 + slot) * 16) =
        make_uint4(m[0] | (m[1] << 16), m[2] | (m[3] << 16), m[4] | (m[5] << 16), m[6] | (m[7] << 16));
    *(uint4*)((char*)A3 + ((wb * 3 + 2) * 64 + slot) * 16) =
        make_uint4(l[0] | (l[1] << 16), l[2] | (l[3] << 16), l[4] | (l[5] << 16), l[6] | (l[7] << 16));
    // stage B: 12 linear global_load_lds per wave
    const uint4* src = MT3 + (size_t)kit * 3072;
#pragma unroll
    for (int i = 0; i < 12; ++i) {
      int gs = (w * 12 + i) * 64;
      gload_lds16(src + gs + lane, B3 + (size_t)gs * 16);
    }
    __syncthreads();
    bfrag ah = *(const bfrag*)((const char*)A3 + ((w * 3 + 0) * 64 + lane) * 16);
    bfrag am = *(const bfrag*)((const char*)A3 + ((w * 3 + 1) * 64 + lane) * 16);
    bfrag al = *(const bfrag*)((const char*)A3 + ((w * 3 + 2) * 64 + lane) * 16);
#pragma unroll
    for (int nf = 0; nf < 16; ++nf) {
      bfrag bh = *(const bfrag*)(B3 + ((nf * 3 + 0) * 64 + lane) * 16);
      bfrag bm = *(const bfrag*)(B3 + ((nf * 3 + 1) * 64 + lane) * 16);
      bfrag bl = *(const bfrag*)(B3 + ((nf * 3 + 2) * 64 + lane) * 16);
      acc[nf] = __builtin_amdgcn_mfma_f32_16x16x32_bf16(ah, bh, acc[nf], 0, 0, 0);
      acc[nf] = __builtin_amdgcn_mfma_f32_16x16x32_bf16(ah, bm, acc[nf], 0, 0, 0);
      acc[nf] = __builtin_amdgcn_mfma_f32_16x16x32_bf16(am, bh, acc[nf], 0, 0, 0);
      acc[nf] = __builtin_amdgcn_mfma_f32_16x16x32_bf16(ah, bl, acc[nf], 0, 0, 0);
      acc[nf] = __builtin_amdgcn_mfma_f32_16x16x32_bf16(al, bh, acc[nf], 0, 0, 0);
      acc[nf] = __builtin_amdgcn_mfma_f32_16x16x32_bf16(am, bm, acc[nf], 0, 0, 0);
    }
    __syncthreads();
  }
  // dump C = (X@M) tile to LDS (overlay; all staging reads done)
#pragma unroll
  for (int nf = 0; nf < 16; ++nf)
#pragma unroll
    for (int reg = 0; reg < 4; ++reg)
      C[(size_t)(16 * w + l4 * 4 + reg) * 260 + nf * 16 + l15] = acc[nf][reg];
  __syncthreads();
  // epilogue: Xprod[row] = sum_d C[row][d] * X[row][d]  (exact f32 x)
  float part = 0.f;
#pragma unroll
  for (int j = 0; j < 16; ++j) {
    f4 xv = *(const f4*)(xrow + g * 64 + 4 * j);
    f4 cv = *(const f4*)&C[(size_t)r * 260 + g * 64 + 4 * j];
    part = fmaf(xv.x, cv.x, fmaf(xv.y, cv.y, fmaf(xv.z, cv.z, fmaf(xv.w, cv.w, part))));
  }
  part += __shfl_xor(part, 1);
  part += __shfl_xor(part, 2);
  if (g == 0 && row0 + r < NT) Xprod[row0 + r] = part;
}

// ------------- cross: MFMA GEMM + per-column running top-5 -------------
__global__ __launch_bounds__(256, 3)
void cross_topk_kernel(const float* __restrict__ X, const uint4* __restrict__ Z2h,
                       const uint4* __restrict__ Z2l, const float* __restrict__ Xprod,
                       float* __restrict__ cand_v, int* __restrict__ cand_i,
                       int NT, int NEVAL) {
  __shared__ short A_hi[RT * KS];
  __shared__ short A_lo[RT * KS];
  __shared__ short B_hi[COLS * KS];
  __shared__ short B_lo[COLS * KS];
  __shared__ float xp_lds[RT];

  const int t = threadIdx.x;
  const int w = t >> 6, lane = t & 63;
  const int l15 = lane & 15, l4 = lane >> 4;
  // XCD-aware bijective swizzle: same-chunk col-tiles land on one XCD (T1)
  int n = blockIdx.y * gridDim.x + blockIdx.x;
  int nwg = gridDim.x * gridDim.y;
  int wg = n;
  if ((nwg & 7) == 0) wg = (n & 7) * (nwg >> 3) + (n >> 3);
  const int ct = wg % gridDim.x;
  const int ch = wg / gridDim.x;
  const int c0 = ct * COLS;
  const int row0 = ch * CHUNK;
  const int rows = min(CHUNK, NT - row0);
  const int ntile = (rows + RT - 1) / RT;

  float bv[2][KNN]; int bi[2][KNN];
#pragma unroll
  for (int nf = 0; nf < 2; ++nf)
#pragma unroll
    for (int s = 0; s < KNN; ++s) { bv[nf][s] = FLT_MAX; bi[nf][s] = 0x7fffffff; }

  for (int rt = 0; rt < ntile; ++rt) {
    const int trow0 = row0 + rt * RT;
    if (t < RT) { int gr = trow0 + t; if (gr >= NT) gr = NT - 1; xp_lds[t] = Xprod[gr]; }
    f32x4 acc[4][2];
#pragma unroll
    for (int mf = 0; mf < 4; ++mf)
#pragma unroll
      for (int nf = 0; nf < 2; ++nf) { f32x4 z = {0.f, 0.f, 0.f, 0.f}; acc[mf][nf] = z; }

    for (int kit = 0; kit < 4; ++kit) {
      const int k0 = kit * KS;
#pragma unroll
      for (int i = 0; i < 4; ++i) {
        int f = t + 256 * i;
        int r = f >> 4, k4 = f & 15;
        int grow = trow0 + r; if (grow >= NT) grow = NT - 1;
        f4 v = *(const f4*)(X + (size_t)grow * DD + k0 + 4 * k4);
        uint32_t h0, l0, h1, l1, h2, l2, h3, l3;
        split2(v.x, h0, l0); split2(v.y, h1, l1);
        split2(v.z, h2, l2); split2(v.w, h3, l3);
        int byte = (r * 128 + 8 * k4) ^ ((r & 7) << 4);
        *(uint2*)((char*)A_hi + byte) = make_uint2(h0 | (h1 << 16), h2 | (h3 << 16));
        *(uint2*)((char*)A_lo + byte) = make_uint2(l0 | (l1 << 16), l2 | (l3 << 16));
      }
      const uint4* srcH = Z2h + (size_t)(ct * 4 + kit) * 1024;
      const uint4* srcL = Z2l + (size_t)(ct * 4 + kit) * 1024;
#pragma unroll
      for (int i = 0; i < 4; ++i) {
        int sl = i * 256 + w * 64;
        gload_lds16(srcH + sl + lane, (char*)B_hi + sl * 16);
        gload_lds16(srcL + sl + lane, (char*)B_lo + sl * 16);
      }
      __syncthreads();
#pragma unroll
      for (int ks = 0; ks < 2; ++ks) {
        bfrag ah[4], al[4], bh[2], bl[2];
#pragma unroll
        for (int mf = 0; mf < 4; ++mf) {
          int mr = mf * 16 + l15;
          int byte = (mr * 128 + ks * 64 + l4 * 16) ^ ((mr & 7) << 4);
          ah[mf] = *(const bfrag*)((const char*)A_hi + byte);
          al[mf] = *(const bfrag*)((const char*)A_lo + byte);
        }
#pragma unroll
        for (int nf = 0; nf < 2; ++nf) {
          int nr = w * 32 + nf * 16 + l15;
          int byte = (nr * 128 + ks * 64 + l4 * 16) ^ ((nr & 7) << 4);
          bh[nf] = *(const bfrag*)((const char*)B_hi + byte);
          bl[nf] = *(const bfrag*)((const char*)B_lo + byte);
        }
#pragma unroll
        for (int mf = 0; mf < 4; ++mf)
#pragma unroll
          for (int nf = 0; nf < 2; ++nf) {
            acc[mf][nf] = __builtin_amdgcn_mfma_f32_16x16x32_bf16(ah[mf], bh[nf], acc[mf][nf], 0, 0, 0);
            acc[mf][nf] = __builtin_amdgcn_mfma_f32_16x16x32_bf16(ah[mf], bl[nf], acc[mf][nf], 0, 0, 0);
            acc[mf][nf] = __builtin_amdgcn_mfma_f32_16x16x32_bf16(al[mf], bh[nf], acc[mf][nf], 0, 0, 0);
          }
      }
      __syncthreads();
    }
#pragma unroll
    for (int mf = 0; mf < 4; ++mf) {
#pragma unroll
      for (int rg = 0; rg < 4; ++rg) {
        int rl = mf * 16 + l4 * 4 + rg;
        int grow = trow0 + rl;
        float xp = xp_lds[rl];
        bool ok = grow < NT;
#pragma unroll
        for (int nf = 0; nf < 2; ++nf) {
          float v = xp + acc[mf][nf][rg];
          if (ok && v < bv[nf][4]) {
            if (v < bv[nf][3]) {
              bv[nf][4] = bv[nf][3]; bi[nf][4] = bi[nf][3];
              if (v < bv[nf][2]) {
                bv[nf][3] = bv[nf][2]; bi[nf][3] = bi[nf][2];
                if (v < bv[nf][1]) {
                  bv[nf][2] = bv[nf][1]; bi[nf][2] = bi[nf][1];
                  if (v < bv[nf][0]) {
                    bv[nf][1] = bv[nf][0]; bi[nf][1] = bi[nf][0];
                    bv[nf][0] = v; bi[nf][0] = grow;
                  } else { bv[nf][1] = v; bi[nf][1] = grow; }
                } else { bv[nf][2] = v; bi[nf][2] = grow; }
              } else { bv[nf][3] = v; bi[nf][3] = grow; }
            } else { bv[nf][4] = v; bi[nf][4] = grow; }
          }
        }
      }
    }
    __syncthreads();
  }
#pragma unroll
  for (int nf = 0; nf < 2; ++nf) {
    int col = c0 + w * 32 + nf * 16 + l15;
    size_t o = (((size_t)ch * NEVAL + col) * NSRC + l4) * KNN;
#pragma unroll
    for (int s = 0; s < KNN; ++s) { cand_v[o + s] = bv[nf][s]; cand_i[o + s] = bi[nf][s]; }
  }
}

// ------------- finalize: merge 980 -> top-10 -> exact rescore -> top-5 -------------
__global__ __launch_bounds__(64)
void finalize_kernel(const float* __restrict__ cand_v, const int* __restrict__ cand_i,
                     const float* __restrict__ X, const float* __restrict__ ZTf32,
                     const float* __restrict__ Xprod, const int* __restrict__ y,
                     float* __restrict__ out, int NCH, int NEVAL, int NT) {
  __shared__ float ztl[DD];
  const int j = blockIdx.x;
  const int lane = threadIdx.x;
#pragma unroll
  for (int i = 0; i < 4; ++i) {
    int k = lane + 64 * i;
    ztl[k] = ZTf32[(size_t)k * NEVAL + j];
  }
  __syncthreads();

  float bv[10]; int bi[10];
#pragma unroll
  for (int s = 0; s < 10; ++s) { bv[s] = FLT_MAX; bi[s] = 0x7fffffff; }
  const int NC = NCH * NSRC * KNN;
  for (int p = lane; p < NC; p += 64) {
    int chq = p / 20, u = p - chq * 20;
    size_t o = ((size_t)chq * NEVAL + j) * 20 + u;
    ins10(bv, bi, cand_v[o], cand_i[o]);
  }
#pragma unroll
  for (int st = 0; st < 6; ++st) {
    float pv[10]; int pi[10];
#pragma unroll
    for (int s = 0; s < 10; ++s) {
      pv[s] = __shfl_xor(bv[s], 1 << st);
      pi[s] = __shfl_xor(bi[s], 1 << st);
    }
#pragma unroll
    for (int s = 0; s < 10; ++s) ins10(bv, bi, pv[s], pi[s]);
  }
  float ex[10];
#pragma unroll
  for (int c = 0; c < 10; ++c) {
    int idx = bi[c];
    float part = 0.f;
#pragma unroll
    for (int i = 0; i < 4; ++i) {
      int k = lane + 64 * i;
      part = fmaf(X[(size_t)idx * DD + k], ztl[k], part);
    }
#pragma unroll
    for (int st = 0; st < 6; ++st) part += __shfl_xor(part, 1 << st);
    ex[c] = Xprod[idx] - 2.f * part;
  }
  float fv[KNN]; int fi[KNN];
#pragma unroll
  for (int s = 0; s < KNN; ++s) { fv[s] = FLT_MAX; fi[s] = 0x7fffffff; }
#pragma unroll
  for (int c = 0; c < 10; ++c) ins5lex(fv, fi, ex[c], bi[c]);
  int lb[KNN];
#pragma unroll
  for (int s = 0; s < KNN; ++s) lb[s] = y[fi[s]];
  for (int q = lane; q < NLAB; q += 64) {
    int cnt = (lb[0] == q) + (lb[1] == q) + (lb[2] == q) + (lb[3] == q) + (lb[4] == q);
    out[(size_t)j * NLAB + q] = (float)cnt - (float)q * 0.01f;
  }
}

extern "C" void kernel_launch(void* const* d_in, const int* in_sizes, int n_in,
                              void* d_out, int out_size, void* d_ws, size_t ws_size,
                              hipStream_t stream) {
  const float* X  = (const float*)d_in[0];
  const float* M  = (const float*)d_in[1];
  const float* Xe = (const float*)d_in[2];
  const int*   y  = (const int*)d_in[3];
  const int NT    = in_sizes[0] / DD;          // 100000
  const int NEVAL = in_sizes[2] / DD;          // 2048
  const int NCH   = (NT + CHUNK - 1) / CHUNK;  // 49

  char* ws = (char*)d_ws;
  uint4* Z2h    = (uint4*)ws;                               // 1 MB
  uint4* Z2l    = (uint4*)(ws + (1 << 20));                 // 1 MB
  float* ZTf32  = (float*)(ws + (2 << 20));                 // 2 MB
  uint4* MT3    = (uint4*)(ws + (4 << 20));                 // 384 KB
  float* Xprod  = (float*)(ws + (4 << 20) + (512 << 10));   // ~400 KB
  float* cand_v = (float*)(ws + (5 << 20));                 // 8.03 MB
  int*   cand_i = (int*)((char*)cand_v + (size_t)NCH * NEVAL * NSRC * KNN * 4);
  float* out    = (float*)d_out;

  msplit_kernel<<<dim3(32), 256, 0, stream>>>(M, MT3);
  prep_kernel<<<dim3(NEVAL / 64, DD / 64), 256, 0, stream>>>(M, Xe, ZTf32, Z2h, Z2l, NEVAL);
  xprod_kernel<<<dim3((NT + 63) / 64), 256, 0, stream>>>(X, MT3, Xprod, NT);
  cross_topk_kernel<<<dim3(NEVAL / COLS, NCH), 256, 0, stream>>>(
      X, Z2h, Z2l, Xprod, cand_v, cand_i, NT, NEVAL);
  finalize_kernel<<<dim3(NEVAL), 64, 0, stream>>>(
      cand_v, cand_i, X, ZTf32, Xprod, y, out, NCH, NEVAL, NT);
}

// Round 4
// 734.919 us; speedup vs baseline: 3.6684x; 1.0281x over previous
//
#include <hip/hip_runtime.h>
#include <cfloat>
#include <cstdint>

// MahalanobisKnnModule v4:
//   msplit:  MT3 = 3-way bf16 split of M, frag-arranged for xprod staging.
//   prep:    ZTf32 = M@Xe^T (exact) + Z2h/Z2l 2-split of -2*ZT^T, staged
//            in swizzled slot order for cross's B global_load_lds.
//   xsplit:  Xh/Xl = 2-split of X, staged in swizzled slot order for
//            cross's A global_load_lds (kills the 16x-redundant in-loop
//            VALU split that capped MfmaUtil at 21%).  [needs ~132MB ws;
//            cross is templated with an on-fly fallback otherwise]
//   xprod:   Xprod[i] = x_i^T M x_i via 3-split MFMA.
//   cross:   S = Xprod[i] - 2*x_i.z_j via 2-split MFMA (hh+hl+lh),
//            per-column running top-5 -> 4 partial lists. XCD-swizzled.
//   final:   merge 980 -> top-10 -> exact f32 rescore -> top-5 -> histogram.

#define DD    256
#define NLAB  100
#define KNN   5
#define COLS  128
#define RT    64
#define KS    64
#define CHUNK 2048
#define NSRC  4

typedef float4 f4;
typedef __attribute__((ext_vector_type(8))) short bfrag;   // 8 bf16
typedef __attribute__((ext_vector_type(4))) float f32x4;

__device__ __forceinline__ void gload_lds16(const void* g, void* l) {
  __builtin_amdgcn_global_load_lds(
      (const __attribute__((address_space(1))) void*)g,
      (__attribute__((address_space(3))) void*)l, 16, 0, 0);
}

// 2-split: round-to-nearest hi, residual lo
__device__ __forceinline__ void split2(float v, uint32_t& h, uint32_t& l) {
  uint32_t b = __float_as_uint(v);
  uint32_t hb = (b + 0x8000u) & 0xffff0000u;
  float lf = v - __uint_as_float(hb);
  h = hb >> 16;
  l = __float_as_uint(lf) >> 16;
}

// 3-split: v ~= h + m + l with missing mass ~2^-25 |v|
__device__ __forceinline__ void split3(float v, uint32_t& h, uint32_t& m, uint32_t& l) {
  uint32_t b = __float_as_uint(v);
  uint32_t hb = (b + 0x8000u) & 0xffff0000u;
  float r1 = v - __uint_as_float(hb);
  uint32_t b1 = __float_as_uint(r1);
  uint32_t mb = (b1 + 0x8000u) & 0xffff0000u;
  float r2 = r1 - __uint_as_float(mb);
  uint32_t lb = (__float_as_uint(r2) + 0x8000u) & 0xffff0000u;
  h = hb >> 16; m = mb >> 16; l = lb >> 16;
}

__device__ __forceinline__ bool lex_lt(float v, int id, float rv, int rid) {
  return (v < rv) || (v == rv && id < rid);
}

__device__ __forceinline__ void ins5lex(float (&bv)[KNN], int (&bi)[KNN], float v, int id) {
  if (!lex_lt(v, id, bv[4], bi[4])) return;
  if (lex_lt(v, id, bv[3], bi[3])) {
    bv[4] = bv[3]; bi[4] = bi[3];
    if (lex_lt(v, id, bv[2], bi[2])) {
      bv[3] = bv[2]; bi[3] = bi[2];
      if (lex_lt(v, id, bv[1], bi[1])) {
        bv[2] = bv[1]; bi[2] = bi[1];
        if (lex_lt(v, id, bv[0], bi[0])) {
          bv[1] = bv[0]; bi[1] = bi[0]; bv[0] = v; bi[0] = id;
        } else { bv[1] = v; bi[1] = id; }
      } else { bv[2] = v; bi[2] = id; }
    } else { bv[3] = v; bi[3] = id; }
  } else { bv[4] = v; bi[4] = id; }
}

__device__ __forceinline__ void ins10(float (&bv)[10], int (&bi)[10], float v, int id) {
  if (!lex_lt(v, id, bv[9], bi[9])) return;
  bool placed = false;
#pragma unroll
  for (int s = 9; s >= 1; --s) {
    if (!placed) {
      if (lex_lt(v, id, bv[s - 1], bi[s - 1])) { bv[s] = bv[s - 1]; bi[s] = bi[s - 1]; }
      else { bv[s] = v; bi[s] = id; placed = true; }
    }
  }
  if (!placed) { bv[0] = v; bi[0] = id; }
}

// ---------- msplit: MT3[kit][nf][s][lane] = 3-split of M[k][d], frag-order ----------
__global__ __launch_bounds__(256)
void msplit_kernel(const float* __restrict__ M, uint4* __restrict__ MT3) {
  int id = blockIdx.x * 256 + threadIdx.x;   // [0, 8192)
  int lane = id & 63;
  int nf = (id >> 6) & 15;
  int kit = id >> 10;                        // [0,8)
  int d = nf * 16 + (lane & 15);
  int kb = kit * 32 + (lane >> 4) * 8;
  uint32_t hw[4], mw[4], lw[4];
#pragma unroll
  for (int e = 0; e < 4; ++e) {
    uint32_t h0, m0, l0, h1, m1, l1;
    split3(M[(size_t)(kb + 2 * e) * DD + d], h0, m0, l0);
    split3(M[(size_t)(kb + 2 * e + 1) * DD + d], h1, m1, l1);
    hw[e] = h0 | (h1 << 16); mw[e] = m0 | (m1 << 16); lw[e] = l0 | (l1 << 16);
  }
  size_t base = (size_t)(kit * 16 + nf) * 3 * 64;
  MT3[base + lane]       = make_uint4(hw[0], hw[1], hw[2], hw[3]);
  MT3[base + 64 + lane]  = make_uint4(mw[0], mw[1], mw[2], mw[3]);
  MT3[base + 128 + lane] = make_uint4(lw[0], lw[1], lw[2], lw[3]);
}

// ---------- xsplit: Xh/Xl[gt][kit][512 slots] = 2-split of X, swizzle baked ----------
__global__ __launch_bounds__(256)
void xsplit_kernel(const float* __restrict__ X, uint4* __restrict__ Xh,
                   uint4* __restrict__ Xl, int NT) {
  int id = blockIdx.x * 256 + threadIdx.x;   // global slot id
  int gt = id >> 11;                         // 64-row tile
  int rem = id & 2047;
  int kit = rem >> 9;                        // k-step
  int p = rem & 511;                         // 16B slot within (tile,kit)
  int r = p >> 3;                            // row 0..63
  int gp = (p & 7) ^ (r & 7);                // source 16B-group (inverse swizzle)
  int row = gt * 64 + r; if (row >= NT) row = NT - 1;
  const float* src = X + (size_t)row * DD + kit * 64 + gp * 8;
  f4 v0 = *(const f4*)src;
  f4 v1 = *(const f4*)(src + 4);
  uint32_t h[8], l[8];
  split2(v0.x, h[0], l[0]); split2(v0.y, h[1], l[1]);
  split2(v0.z, h[2], l[2]); split2(v0.w, h[3], l[3]);
  split2(v1.x, h[4], l[4]); split2(v1.y, h[5], l[5]);
  split2(v1.z, h[6], l[6]); split2(v1.w, h[7], l[7]);
  Xh[id] = make_uint4(h[0] | (h[1] << 16), h[2] | (h[3] << 16),
                      h[4] | (h[5] << 16), h[6] | (h[7] << 16));
  Xl[id] = make_uint4(l[0] | (l[1] << 16), l[2] | (l[3] << 16),
                      l[4] | (l[5] << 16), l[6] | (l[7] << 16));
}

// ---------- prep: ZTf32 + arranged/swizzled bf16 2-split of -2*ZT^T ----------
__global__ __launch_bounds__(256)
void prep_kernel(const float* __restrict__ M, const float* __restrict__ Xe,
                 float* __restrict__ ZTf32, uint4* __restrict__ Z2h,
                 uint4* __restrict__ Z2l, int NEVAL) {
  __shared__ float xe_lds[64 * 257];
  const int t = threadIdx.x;
  const int j0 = blockIdx.x * 64;
  const int part = t >> 6;
  const int dbase = blockIdx.y * 64 + part * 16;
#pragma unroll
  for (int it = 0; it < 16; ++it) {
    int id = t + it * 256;
    int r = id >> 6, k4 = id & 63;
    f4 v = *(const f4*)(Xe + (size_t)(j0 + r) * DD + 4 * k4);
    float* p = &xe_lds[r * 257 + 4 * k4];
    p[0] = v.x; p[1] = v.y; p[2] = v.z; p[3] = v.w;
  }
  __syncthreads();
  const int j = t & 63;
  float acc[16];
#pragma unroll
  for (int dd = 0; dd < 16; ++dd) acc[dd] = 0.f;
  for (int k4 = 0; k4 < 64; ++k4) {
    const float* xp = &xe_lds[j * 257 + 4 * k4];
    float x0 = xp[0], x1 = xp[1], x2 = xp[2], x3 = xp[3];
#pragma unroll
    for (int dd = 0; dd < 16; ++dd) {
      f4 m = *(const f4*)(M + (size_t)(dbase + dd) * DD + 4 * k4);
      acc[dd] = fmaf(m.x, x0, fmaf(m.y, x1, fmaf(m.z, x2, fmaf(m.w, x3, acc[dd]))));
    }
  }
  const int jg = j0 + j;
#pragma unroll
  for (int dd = 0; dd < 16; ++dd)
    ZTf32[(size_t)(dbase + dd) * NEVAL + jg] = acc[dd];
  const int cc = jg & 127, ct2 = jg >> 7;
  const int kit = dbase >> 6;
  const int sbase = (dbase & 63) >> 3;
#pragma unroll
  for (int half = 0; half < 2; ++half) {
    int s = sbase + half;
    uint32_t hw[4], lw[4];
#pragma unroll
    for (int e = 0; e < 4; ++e) {
      uint32_t h0, l0, h1, l1;
      split2(-2.f * acc[half * 8 + 2 * e], h0, l0);
      split2(-2.f * acc[half * 8 + 2 * e + 1], h1, l1);
      hw[e] = h0 | (h1 << 16);
      lw[e] = l0 | (l1 << 16);
    }
    int pi = 8 * cc + (s ^ (cc & 7));
    size_t o = (size_t)(ct2 * 4 + kit) * 1024 + pi;
    Z2h[o] = make_uint4(hw[0], hw[1], hw[2], hw[3]);
    Z2l[o] = make_uint4(lw[0], lw[1], lw[2], lw[3]);
  }
}

// ---------- xprod: 3-split MFMA GEMM + fused row-dot ----------
__global__ __launch_bounds__(256, 2)
void xprod_kernel(const float* __restrict__ X, const uint4* __restrict__ MT3,
                  float* __restrict__ Xprod, int NT) {
  __shared__ __align__(16) char pool[66560];
  short* A3 = (short*)pool;                  // 12 KB
  char*  B3 = pool + 12288;                  // 48 KB
  float* C  = (float*)pool;                  // [64][260] overlay

  const int t = threadIdx.x;
  const int w = t >> 6, lane = t & 63;
  const int l15 = lane & 15, l4 = lane >> 4;
  const int row0 = blockIdx.x * 64;
  const int r = t >> 2, g = t & 3;
  int grow = row0 + r; if (grow >= NT) grow = NT - 1;
  const float* xrow = X + (size_t)grow * DD;

  f32x4 acc[16];
#pragma unroll
  for (int nf = 0; nf < 16; ++nf) { f32x4 z = {0.f, 0.f, 0.f, 0.f}; acc[nf] = z; }

  for (int kit = 0; kit < 8; ++kit) {
    f4 v0 = *(const f4*)(xrow + kit * 32 + g * 8);
    f4 v1 = *(const f4*)(xrow + kit * 32 + g * 8 + 4);
    uint32_t h[8], m[8], l[8];
    split3(v0.x, h[0], m[0], l[0]); split3(v0.y, h[1], m[1], l[1]);
    split3(v0.z, h[2], m[2], l[2]); split3(v0.w, h[3], m[3], l[3]);
    split3(v1.x, h[4], m[4], l[4]); split3(v1.y, h[5], m[5], l[5]);
    split3(v1.z, h[6], m[6], l[6]); split3(v1.w, h[7], m[7], l[7]);
    int slot = (r & 15) + 16 * g;
    int wb = r >> 4;
    *(uint4*)((char*)A3 + ((wb * 3 + 0) * 64 + slot) * 16) =
        make_uint4(h[0] | (h[1] << 16), h[2] | (h[3] << 16), h[4] | (h[5] << 16), h[6] | (h[7] << 16));
    *(uint4*)((char*)A3 + ((wb * 3 + 1) * 64 + slot) * 16) =
        make_uint4(m[0] | (m[1] << 16), m[2] | (m[3] << 16), m[4] | (m[5] << 16), m[6] | (m[7] << 16));
    *(uint4*)((char*)A3 + ((wb * 3 + 2) * 64 + slot) * 16) =
        make_uint4(l[0] | (l[1] << 16), l[2] | (l[3] << 16), l[4] | (l[5] << 16), l[6] | (l[7] << 16));
    const uint4* src = MT3 + (size_t)kit * 3072;
#pragma unroll
    for (int i = 0; i < 12; ++i) {
      int gs = (w * 12 + i) * 64;
      gload_lds16(src + gs + lane, B3 + (size_t)gs * 16);
    }
    __syncthreads();
    bfrag ah = *(const bfrag*)((const char*)A3 + ((w * 3 + 0) * 64 + lane) * 16);
    bfrag am = *(const bfrag*)((const char*)A3 + ((w * 3 + 1) * 64 + lane) * 16);
    bfrag al = *(const bfrag*)((const char*)A3 + ((w * 3 + 2) * 64 + lane) * 16);
#pragma unroll
    for (int nf = 0; nf < 16; ++nf) {
      bfrag bh = *(const bfrag*)(B3 + ((nf * 3 + 0) * 64 + lane) * 16);
      bfrag bm = *(const bfrag*)(B3 + ((nf * 3 + 1) * 64 + lane) * 16);
      bfrag bl = *(const bfrag*)(B3 + ((nf * 3 + 2) * 64 + lane) * 16);
      acc[nf] = __builtin_amdgcn_mfma_f32_16x16x32_bf16(ah, bh, acc[nf], 0, 0, 0);
      acc[nf] = __builtin_amdgcn_mfma_f32_16x16x32_bf16(ah, bm, acc[nf], 0, 0, 0);
      acc[nf] = __builtin_amdgcn_mfma_f32_16x16x32_bf16(am, bh, acc[nf], 0, 0, 0);
      acc[nf] = __builtin_amdgcn_mfma_f32_16x16x32_bf16(ah, bl, acc[nf], 0, 0, 0);
      acc[nf] = __builtin_amdgcn_mfma_f32_16x16x32_bf16(al, bh, acc[nf], 0, 0, 0);
      acc[nf] = __builtin_amdgcn_mfma_f32_16x16x32_bf16(am, bm, acc[nf], 0, 0, 0);
    }
    __syncthreads();
  }
#pragma unroll
  for (int nf = 0; nf < 16; ++nf)
#pragma unroll
    for (int reg = 0; reg < 4; ++reg)
      C[(size_t)(16 * w + l4 * 4 + reg) * 260 + nf * 16 + l15] = acc[nf][reg];
  __syncthreads();
  float part = 0.f;
#pragma unroll
  for (int j = 0; j < 16; ++j) {
    f4 xv = *(const f4*)(xrow + g * 64 + 4 * j);
    f4 cv = *(const f4*)&C[(size_t)r * 260 + g * 64 + 4 * j];
    part = fmaf(xv.x, cv.x, fmaf(xv.y, cv.y, fmaf(xv.z, cv.z, fmaf(xv.w, cv.w, part))));
  }
  part += __shfl_xor(part, 1);
  part += __shfl_xor(part, 2);
  if (g == 0 && row0 + r < NT) Xprod[row0 + r] = part;
}

// ------------- cross: MFMA GEMM + per-column running top-5 -------------
template <int PRE>
__global__ __launch_bounds__(256, 3)
void cross_topk_kernel(const float* __restrict__ X, const uint4* __restrict__ Xh,
                       const uint4* __restrict__ Xl, const uint4* __restrict__ Z2h,
                       const uint4* __restrict__ Z2l, const float* __restrict__ Xprod,
                       float* __restrict__ cand_v, int* __restrict__ cand_i,
                       int NT, int NEVAL) {
  __shared__ short A_hi[RT * KS];
  __shared__ short A_lo[RT * KS];
  __shared__ short B_hi[COLS * KS];
  __shared__ short B_lo[COLS * KS];
  __shared__ float xp_lds[RT];

  const int t = threadIdx.x;
  const int w = t >> 6, lane = t & 63;
  const int l15 = lane & 15, l4 = lane >> 4;
  int n = blockIdx.y * gridDim.x + blockIdx.x;
  int nwg = gridDim.x * gridDim.y;
  int wg = n;
  if ((nwg & 7) == 0) wg = (n & 7) * (nwg >> 3) + (n >> 3);
  const int ct = wg % gridDim.x;
  const int ch = wg / gridDim.x;
  const int c0 = ct * COLS;
  const int row0 = ch * CHUNK;
  const int rows = min(CHUNK, NT - row0);
  const int ntile = (rows + RT - 1) / RT;

  float bv[2][KNN]; int bi[2][KNN];
#pragma unroll
  for (int nf = 0; nf < 2; ++nf)
#pragma unroll
    for (int s = 0; s < KNN; ++s) { bv[nf][s] = FLT_MAX; bi[nf][s] = 0x7fffffff; }

  for (int rt = 0; rt < ntile; ++rt) {
    const int trow0 = row0 + rt * RT;
    if (t < RT) { int gr = trow0 + t; if (gr >= NT) gr = NT - 1; xp_lds[t] = Xprod[gr]; }
    f32x4 acc[4][2];
#pragma unroll
    for (int mf = 0; mf < 4; ++mf)
#pragma unroll
      for (int nf = 0; nf < 2; ++nf) { f32x4 z = {0.f, 0.f, 0.f, 0.f}; acc[mf][nf] = z; }

    for (int kit = 0; kit < 4; ++kit) {
      const int k0 = kit * KS;
      if constexpr (PRE) {
        // A pre-split in HBM, swizzle baked: pure linear global_load_lds
        const uint4* sAh = Xh + ((size_t)(trow0 >> 6) * 4 + kit) * 512;
        const uint4* sAl = Xl + ((size_t)(trow0 >> 6) * 4 + kit) * 512;
#pragma unroll
        for (int i = 0; i < 2; ++i) {
          int sl = (i * 4 + w) * 64;
          gload_lds16(sAh + sl + lane, (char*)A_hi + sl * 16);
          gload_lds16(sAl + sl + lane, (char*)A_lo + sl * 16);
        }
      } else {
        // fallback: on-the-fly split (VALU-heavy)
#pragma unroll
        for (int i = 0; i < 4; ++i) {
          int f = t + 256 * i;
          int r = f >> 4, k4 = f & 15;
          int grow = trow0 + r; if (grow >= NT) grow = NT - 1;
          f4 v = *(const f4*)(X + (size_t)grow * DD + k0 + 4 * k4);
          uint32_t h0, l0, h1, l1, h2, l2, h3, l3;
          split2(v.x, h0, l0); split2(v.y, h1, l1);
          split2(v.z, h2, l2); split2(v.w, h3, l3);
          int byte = (r * 128 + 8 * k4) ^ ((r & 7) << 4);
          *(uint2*)((char*)A_hi + byte) = make_uint2(h0 | (h1 << 16), h2 | (h3 << 16));
          *(uint2*)((char*)A_lo + byte) = make_uint2(l0 | (l1 << 16), l2 | (l3 << 16));
        }
      }
      const uint4* srcH = Z2h + (size_t)(ct * 4 + kit) * 1024;
      const uint4* srcL = Z2l + (size_t)(ct * 4 + kit) * 1024;
#pragma unroll
      for (int i = 0; i < 4; ++i) {
        int sl = i * 256 + w * 64;
        gload_lds16(srcH + sl + lane, (char*)B_hi + sl * 16);
        gload_lds16(srcL + sl + lane, (char*)B_lo + sl * 16);
      }
      __syncthreads();
#pragma unroll
      for (int ks = 0; ks < 2; ++ks) {
        bfrag ah[4], al[4], bh[2], bl[2];
#pragma unroll
        for (int mf = 0; mf < 4; ++mf) {
          int mr = mf * 16 + l15;
          int byte = (mr * 128 + ks * 64 + l4 * 16) ^ ((mr & 7) << 4);
          ah[mf] = *(const bfrag*)((const char*)A_hi + byte);
          al[mf] = *(const bfrag*)((const char*)A_lo + byte);
        }
#pragma unroll
        for (int nf = 0; nf < 2; ++nf) {
          int nr = w * 32 + nf * 16 + l15;
          int byte = (nr * 128 + ks * 64 + l4 * 16) ^ ((nr & 7) << 4);
          bh[nf] = *(const bfrag*)((const char*)B_hi + byte);
          bl[nf] = *(const bfrag*)((const char*)B_lo + byte);
        }
#pragma unroll
        for (int mf = 0; mf < 4; ++mf)
#pragma unroll
          for (int nf = 0; nf < 2; ++nf) {
            acc[mf][nf] = __builtin_amdgcn_mfma_f32_16x16x32_bf16(ah[mf], bh[nf], acc[mf][nf], 0, 0, 0);
            acc[mf][nf] = __builtin_amdgcn_mfma_f32_16x16x32_bf16(ah[mf], bl[nf], acc[mf][nf], 0, 0, 0);
            acc[mf][nf] = __builtin_amdgcn_mfma_f32_16x16x32_bf16(al[mf], bh[nf], acc[mf][nf], 0, 0, 0);
          }
      }
      __syncthreads();
    }
#pragma unroll
    for (int mf = 0; mf < 4; ++mf) {
#pragma unroll
      for (int rg = 0; rg < 4; ++rg) {
        int rl = mf * 16 + l4 * 4 + rg;
        int grow = trow0 + rl;
        float xp = xp_lds[rl];
        bool ok = grow < NT;
#pragma unroll
        for (int nf = 0; nf < 2; ++nf) {
          float v = xp + acc[mf][nf][rg];
          if (ok && v < bv[nf][4]) {
            if (v < bv[nf][3]) {
              bv[nf][4] = bv[nf][3]; bi[nf][4] = bi[nf][3];
              if (v < bv[nf][2]) {
                bv[nf][3] = bv[nf][2]; bi[nf][3] = bi[nf][2];
                if (v < bv[nf][1]) {
                  bv[nf][2] = bv[nf][1]; bi[nf][2] = bi[nf][1];
                  if (v < bv[nf][0]) {
                    bv[nf][1] = bv[nf][0]; bi[nf][1] = bi[nf][0];
                    bv[nf][0] = v; bi[nf][0] = grow;
                  } else { bv[nf][1] = v; bi[nf][1] = grow; }
                } else { bv[nf][2] = v; bi[nf][2] = grow; }
              } else { bv[nf][3] = v; bi[nf][3] = grow; }
            } else { bv[nf][4] = v; bi[nf][4] = grow; }
          }
        }
      }
    }
    __syncthreads();
  }
#pragma unroll
  for (int nf = 0; nf < 2; ++nf) {
    int col = c0 + w * 32 + nf * 16 + l15;
    size_t o = (((size_t)ch * NEVAL + col) * NSRC + l4) * KNN;
#pragma unroll
    for (int s = 0; s < KNN; ++s) { cand_v[o + s] = bv[nf][s]; cand_i[o + s] = bi[nf][s]; }
  }
}

// ------------- finalize: merge 980 -> top-10 -> exact rescore -> top-5 -------------
__global__ __launch_bounds__(64)
void finalize_kernel(const float* __restrict__ cand_v, const int* __restrict__ cand_i,
                     const float* __restrict__ X, const float* __restrict__ ZTf32,
                     const float* __restrict__ Xprod, const int* __restrict__ y,
                     float* __restrict__ out, int NCH, int NEVAL, int NT) {
  __shared__ float ztl[DD];
  const int j = blockIdx.x;
  const int lane = threadIdx.x;
#pragma unroll
  for (int i = 0; i < 4; ++i) {
    int k = lane + 64 * i;
    ztl[k] = ZTf32[(size_t)k * NEVAL + j];
  }
  __syncthreads();

  float bv[10]; int bi[10];
#pragma unroll
  for (int s = 0; s < 10; ++s) { bv[s] = FLT_MAX; bi[s] = 0x7fffffff; }
  const int NC = NCH * NSRC * KNN;
  for (int p = lane; p < NC; p += 64) {
    int chq = p / 20, u = p - chq * 20;
    size_t o = ((size_t)chq * NEVAL + j) * 20 + u;
    ins10(bv, bi, cand_v[o], cand_i[o]);
  }
#pragma unroll
  for (int st = 0; st < 6; ++st) {
    float pv[10]; int pi[10];
#pragma unroll
    for (int s = 0; s < 10; ++s) {
      pv[s] = __shfl_xor(bv[s], 1 << st);
      pi[s] = __shfl_xor(bi[s], 1 << st);
    }
#pragma unroll
    for (int s = 0; s < 10; ++s) ins10(bv, bi, pv[s], pi[s]);
  }
  float ex[10];
#pragma unroll
  for (int c = 0; c < 10; ++c) {
    int idx = bi[c];
    float part = 0.f;
#pragma unroll
    for (int i = 0; i < 4; ++i) {
      int k = lane + 64 * i;
      part = fmaf(X[(size_t)idx * DD + k], ztl[k], part);
    }
#pragma unroll
    for (int st = 0; st < 6; ++st) part += __shfl_xor(part, 1 << st);
    ex[c] = Xprod[idx] - 2.f * part;
  }
  float fv[KNN]; int fi[KNN];
#pragma unroll
  for (int s = 0; s < KNN; ++s) { fv[s] = FLT_MAX; fi[s] = 0x7fffffff; }
#pragma unroll
  for (int c = 0; c < 10; ++c) ins5lex(fv, fi, ex[c], bi[c]);
  int lb[KNN];
#pragma unroll
  for (int s = 0; s < KNN; ++s) lb[s] = y[fi[s]];
  for (int q = lane; q < NLAB; q += 64) {
    int cnt = (lb[0] == q) + (lb[1] == q) + (lb[2] == q) + (lb[3] == q) + (lb[4] == q);
    out[(size_t)j * NLAB + q] = (float)cnt - (float)q * 0.01f;
  }
}

extern "C" void kernel_launch(void* const* d_in, const int* in_sizes, int n_in,
                              void* d_out, int out_size, void* d_ws, size_t ws_size,
                              hipStream_t stream) {
  const float* X  = (const float*)d_in[0];
  const float* M  = (const float*)d_in[1];
  const float* Xe = (const float*)d_in[2];
  const int*   y  = (const int*)d_in[3];
  const int NT    = in_sizes[0] / DD;          // 100000
  const int NEVAL = in_sizes[2] / DD;          // 2048
  const int NCH   = (NT + CHUNK - 1) / CHUNK;  // 49
  const int NT64  = (NT + 63) / 64;            // 1563

  char* ws = (char*)d_ws;
  uint4* Z2h    = (uint4*)ws;                               // 1 MB
  uint4* Z2l    = (uint4*)(ws + (1 << 20));                 // 1 MB
  float* ZTf32  = (float*)(ws + (2 << 20));                 // 2 MB
  uint4* MT3    = (uint4*)(ws + (4 << 20));                 // 384 KB
  float* Xprod  = (float*)(ws + (4 << 20) + (512 << 10));   // ~400 KB
  float* cand_v = (float*)(ws + (5 << 20));                 // 8.03 MB
  int*   cand_i = (int*)((char*)cand_v + (size_t)NCH * NEVAL * NSRC * KNN * 4);
  uint4* Xh     = (uint4*)(ws + (24ULL << 20));             // NT64*32 KB = 51.2 MB
  uint4* Xl     = (uint4*)(ws + (80ULL << 20));             // 51.2 MB
  float* out    = (float*)d_out;

  const size_t need = (80ULL << 20) + (size_t)NT64 * 32768;
  const bool pre = ws_size >= need;

  msplit_kernel<<<dim3(32), 256, 0, stream>>>(M, MT3);
  prep_kernel<<<dim3(NEVAL / 64, DD / 64), 256, 0, stream>>>(M, Xe, ZTf32, Z2h, Z2l, NEVAL);
  if (pre) xsplit_kernel<<<dim3(NT64 * 8), 256, 0, stream>>>(X, Xh, Xl, NT);
  xprod_kernel<<<dim3(NT64), 256, 0, stream>>>(X, MT3, Xprod, NT);
  if (pre)
    cross_topk_kernel<1><<<dim3(NEVAL / COLS, NCH), 256, 0, stream>>>(
        X, Xh, Xl, Z2h, Z2l, Xprod, cand_v, cand_i, NT, NEVAL);
  else
    cross_topk_kernel<0><<<dim3(NEVAL / COLS, NCH), 256, 0, stream>>>(
        X, Xh, Xl, Z2h, Z2l, Xprod, cand_v, cand_i, NT, NEVAL);
  finalize_kernel<<<dim3(NEVAL), 64, 0, stream>>>(
      cand_v, cand_i, X, ZTf32, Xprod, y, out, NCH, NEVAL, NT);
}

// Round 5
// 701.462 us; speedup vs baseline: 3.8433x; 1.0477x over previous
//
#include <hip/hip_runtime.h>
#include <cfloat>
#include <cstdint>

// MahalanobisKnnModule v5: counted-vmcnt pipelined cross kernel.
//   msplit:  MT3 = 3-way bf16 split of M (xprod staging order).
//   prep:    ZTf32 = M@Xe^T (exact) + Z2 = 2-split of -2*ZT^T in oct-swizzled
//            128B-per-column rows, [ct=16][kit32=8][1024 slots].
//   xsplit:  Xsp = 2-split of X, oct-swizzled 128B-per-row tiles,
//            [tile128][kit32=8][1024 slots].
//   xprod:   x_i^T M x_i via 3-split MFMA (unchanged).
//   cross:   S = Xprod[i] - 2*x_i.z_j via 2-split MFMA (hh+hl+lh).
//            128-row pairs x 128 cols per block, KS=32 phases, A/B LDS
//            double-buffered, stage(g+1) issued before compute(g),
//            s_waitcnt vmcnt(8) (never 0 in main loop), setprio around MFMA.
//   final:   merge 980 -> top-10 -> exact f32 rescore -> top-5 -> histogram.

#define DD    256
#define NLAB  100
#define KNN   5
#define COLS  128
#define CHUNK 2048
#define NSRC  4

typedef float4 f4;
typedef __attribute__((ext_vector_type(8))) short bfrag;   // 8 bf16
typedef __attribute__((ext_vector_type(4))) float f32x4;

__device__ __forceinline__ void gload_lds16(const void* g, void* l) {
  __builtin_amdgcn_global_load_lds(
      (const __attribute__((address_space(1))) void*)g,
      (__attribute__((address_space(3))) void*)l, 16, 0, 0);
}

__device__ __forceinline__ void split2(float v, uint32_t& h, uint32_t& l) {
  uint32_t b = __float_as_uint(v);
  uint32_t hb = (b + 0x8000u) & 0xffff0000u;
  float lf = v - __uint_as_float(hb);
  h = hb >> 16;
  l = __float_as_uint(lf) >> 16;
}

__device__ __forceinline__ void split3(float v, uint32_t& h, uint32_t& m, uint32_t& l) {
  uint32_t b = __float_as_uint(v);
  uint32_t hb = (b + 0x8000u) & 0xffff0000u;
  float r1 = v - __uint_as_float(hb);
  uint32_t b1 = __float_as_uint(r1);
  uint32_t mb = (b1 + 0x8000u) & 0xffff0000u;
  float r2 = r1 - __uint_as_float(mb);
  uint32_t lb = (__float_as_uint(r2) + 0x8000u) & 0xffff0000u;
  h = hb >> 16; m = mb >> 16; l = lb >> 16;
}

__device__ __forceinline__ bool lex_lt(float v, int id, float rv, int rid) {
  return (v < rv) || (v == rv && id < rid);
}

__device__ __forceinline__ void ins5run(float (&bv)[KNN], int (&bi)[KNN], float v, int id) {
  // running insert during scan: strictly-less keeps earliest id (ids ascend)
  if (v < bv[4]) {
    if (v < bv[3]) {
      bv[4] = bv[3]; bi[4] = bi[3];
      if (v < bv[2]) {
        bv[3] = bv[2]; bi[3] = bi[2];
        if (v < bv[1]) {
          bv[2] = bv[1]; bi[2] = bi[1];
          if (v < bv[0]) {
            bv[1] = bv[0]; bi[1] = bi[0]; bv[0] = v; bi[0] = id;
          } else { bv[1] = v; bi[1] = id; }
        } else { bv[2] = v; bi[2] = id; }
      } else { bv[3] = v; bi[3] = id; }
    } else { bv[4] = v; bi[4] = id; }
  }
}

__device__ __forceinline__ void ins5lex(float (&bv)[KNN], int (&bi)[KNN], float v, int id) {
  if (!lex_lt(v, id, bv[4], bi[4])) return;
  if (lex_lt(v, id, bv[3], bi[3])) {
    bv[4] = bv[3]; bi[4] = bi[3];
    if (lex_lt(v, id, bv[2], bi[2])) {
      bv[3] = bv[2]; bi[3] = bi[2];
      if (lex_lt(v, id, bv[1], bi[1])) {
        bv[2] = bv[1]; bi[2] = bi[1];
        if (lex_lt(v, id, bv[0], bi[0])) {
          bv[1] = bv[0]; bi[1] = bi[0]; bv[0] = v; bi[0] = id;
        } else { bv[1] = v; bi[1] = id; }
      } else { bv[2] = v; bi[2] = id; }
    } else { bv[3] = v; bi[3] = id; }
  } else { bv[4] = v; bi[4] = id; }
}

__device__ __forceinline__ void ins10(float (&bv)[10], int (&bi)[10], float v, int id) {
  if (!lex_lt(v, id, bv[9], bi[9])) return;
  bool placed = false;
#pragma unroll
  for (int s = 9; s >= 1; --s) {
    if (!placed) {
      if (lex_lt(v, id, bv[s - 1], bi[s - 1])) { bv[s] = bv[s - 1]; bi[s] = bi[s - 1]; }
      else { bv[s] = v; bi[s] = id; placed = true; }
    }
  }
  if (!placed) { bv[0] = v; bi[0] = id; }
}

// ---------- msplit: MT3 = 3-split of M, frag order for xprod ----------
__global__ __launch_bounds__(256)
void msplit_kernel(const float* __restrict__ M, uint4* __restrict__ MT3) {
  int id = blockIdx.x * 256 + threadIdx.x;   // [0, 8192)
  int lane = id & 63;
  int nf = (id >> 6) & 15;
  int kit = id >> 10;
  int d = nf * 16 + (lane & 15);
  int kb = kit * 32 + (lane >> 4) * 8;
  uint32_t hw[4], mw[4], lw[4];
#pragma unroll
  for (int e = 0; e < 4; ++e) {
    uint32_t h0, m0, l0, h1, m1, l1;
    split3(M[(size_t)(kb + 2 * e) * DD + d], h0, m0, l0);
    split3(M[(size_t)(kb + 2 * e + 1) * DD + d], h1, m1, l1);
    hw[e] = h0 | (h1 << 16); mw[e] = m0 | (m1 << 16); lw[e] = l0 | (l1 << 16);
  }
  size_t base = (size_t)(kit * 16 + nf) * 3 * 64;
  MT3[base + lane]       = make_uint4(hw[0], hw[1], hw[2], hw[3]);
  MT3[base + 64 + lane]  = make_uint4(mw[0], mw[1], mw[2], mw[3]);
  MT3[base + 128 + lane] = make_uint4(lw[0], lw[1], lw[2], lw[3]);
}

// ---------- xsplit: Xsp[tile][kit][1024]: oct-swizzled 2-split of X ----------
// slot s (of 1024): row m = s>>3, pos = s&7, oct o = pos ^ (m&7);
// o<4: hi half of k-oct o; o>=4: lo half of k-oct o-4.
__global__ __launch_bounds__(256)
void xsplit_kernel(const float* __restrict__ X, uint4* __restrict__ Xsp,
                   int NT, int NTILE) {
  int id = blockIdx.x * 256 + threadIdx.x;   // (tile, kit, m, oq)
  int tile = id >> 12;
  if (tile >= NTILE) return;
  int rem = id & 4095;
  int kit = rem >> 9;
  int m = (rem >> 2) & 127;
  int oq = rem & 3;
  int row = tile * 128 + m; if (row >= NT) row = NT - 1;
  const float* src = X + (size_t)row * DD + kit * 32 + oq * 8;
  f4 v0 = *(const f4*)src;
  f4 v1 = *(const f4*)(src + 4);
  uint32_t h[8], l[8];
  split2(v0.x, h[0], l[0]); split2(v0.y, h[1], l[1]);
  split2(v0.z, h[2], l[2]); split2(v0.w, h[3], l[3]);
  split2(v1.x, h[4], l[4]); split2(v1.y, h[5], l[5]);
  split2(v1.z, h[6], l[6]); split2(v1.w, h[7], l[7]);
  size_t base = ((size_t)tile * 8 + kit) * 1024 + m * 8;
  Xsp[base + (oq ^ (m & 7))] =
      make_uint4(h[0] | (h[1] << 16), h[2] | (h[3] << 16),
                 h[4] | (h[5] << 16), h[6] | (h[7] << 16));
  Xsp[base + ((oq + 4) ^ (m & 7))] =
      make_uint4(l[0] | (l[1] << 16), l[2] | (l[3] << 16),
                 l[4] | (l[5] << 16), l[6] | (l[7] << 16));
}

// ---------- prep: ZTf32 + Z2[ct][kit32][1024] oct-swizzled -2*ZT^T ----------
__global__ __launch_bounds__(256)
void prep_kernel(const float* __restrict__ M, const float* __restrict__ Xe,
                 float* __restrict__ ZTf32, uint4* __restrict__ Z2, int NEVAL) {
  __shared__ float xe_lds[64 * 257];
  const int t = threadIdx.x;
  const int j0 = blockIdx.x * 64;
  const int part = t >> 6;
  const int dbase = blockIdx.y * 64 + part * 16;
#pragma unroll
  for (int it = 0; it < 16; ++it) {
    int id = t + it * 256;
    int r = id >> 6, k4 = id & 63;
    f4 v = *(const f4*)(Xe + (size_t)(j0 + r) * DD + 4 * k4);
    float* p = &xe_lds[r * 257 + 4 * k4];
    p[0] = v.x; p[1] = v.y; p[2] = v.z; p[3] = v.w;
  }
  __syncthreads();
  const int j = t & 63;
  float acc[16];
#pragma unroll
  for (int dd = 0; dd < 16; ++dd) acc[dd] = 0.f;
  for (int k4 = 0; k4 < 64; ++k4) {
    const float* xp = &xe_lds[j * 257 + 4 * k4];
    float x0 = xp[0], x1 = xp[1], x2 = xp[2], x3 = xp[3];
#pragma unroll
    for (int dd = 0; dd < 16; ++dd) {
      f4 m = *(const f4*)(M + (size_t)(dbase + dd) * DD + 4 * k4);
      acc[dd] = fmaf(m.x, x0, fmaf(m.y, x1, fmaf(m.z, x2, fmaf(m.w, x3, acc[dd]))));
    }
  }
  const int jg = j0 + j;
#pragma unroll
  for (int dd = 0; dd < 16; ++dd)
    ZTf32[(size_t)(dbase + dd) * NEVAL + jg] = acc[dd];
  // Z2 write: this thread covers k-octs obase,obase+1 of kit32 for column jg
  const int cc = jg & 127, ct2 = jg >> 7;
  const int kit32 = dbase >> 5;
  const int obase = (dbase & 31) >> 3;       // 0 or 2
  size_t zbase = ((size_t)ct2 * 8 + kit32) * 1024 + cc * 8;
#pragma unroll
  for (int u = 0; u < 2; ++u) {
    int oq = obase + u;
    uint32_t hw[4], lw[4];
#pragma unroll
    for (int e = 0; e < 4; ++e) {
      uint32_t h0, l0, h1, l1;
      split2(-2.f * acc[u * 8 + 2 * e], h0, l0);
      split2(-2.f * acc[u * 8 + 2 * e + 1], h1, l1);
      hw[e] = h0 | (h1 << 16);
      lw[e] = l0 | (l1 << 16);
    }
    Z2[zbase + (oq ^ (cc & 7))]       = make_uint4(hw[0], hw[1], hw[2], hw[3]);
    Z2[zbase + ((oq + 4) ^ (cc & 7))] = make_uint4(lw[0], lw[1], lw[2], lw[3]);
  }
}

// ---------- xprod: 3-split MFMA GEMM + fused row-dot (unchanged) ----------
__global__ __launch_bounds__(256, 2)
void xprod_kernel(const float* __restrict__ X, const uint4* __restrict__ MT3,
                  float* __restrict__ Xprod, int NT) {
  __shared__ __align__(16) char pool[66560];
  short* A3 = (short*)pool;
  char*  B3 = pool + 12288;
  float* C  = (float*)pool;

  const int t = threadIdx.x;
  const int w = t >> 6, lane = t & 63;
  const int l15 = lane & 15, l4 = lane >> 4;
  const int row0 = blockIdx.x * 64;
  const int r = t >> 2, g = t & 3;
  int grow = row0 + r; if (grow >= NT) grow = NT - 1;
  const float* xrow = X + (size_t)grow * DD;

  f32x4 acc[16];
#pragma unroll
  for (int nf = 0; nf < 16; ++nf) { f32x4 z = {0.f, 0.f, 0.f, 0.f}; acc[nf] = z; }

  for (int kit = 0; kit < 8; ++kit) {
    f4 v0 = *(const f4*)(xrow + kit * 32 + g * 8);
    f4 v1 = *(const f4*)(xrow + kit * 32 + g * 8 + 4);
    uint32_t h[8], m[8], l[8];
    split3(v0.x, h[0], m[0], l[0]); split3(v0.y, h[1], m[1], l[1]);
    split3(v0.z, h[2], m[2], l[2]); split3(v0.w, h[3], m[3], l[3]);
    split3(v1.x, h[4], m[4], l[4]); split3(v1.y, h[5], m[5], l[5]);
    split3(v1.z, h[6], m[6], l[6]); split3(v1.w, h[7], m[7], l[7]);
    int slot = (r & 15) + 16 * g;
    int wb = r >> 4;
    *(uint4*)((char*)A3 + ((wb * 3 + 0) * 64 + slot) * 16) =
        make_uint4(h[0] | (h[1] << 16), h[2] | (h[3] << 16), h[4] | (h[5] << 16), h[6] | (h[7] << 16));
    *(uint4*)((char*)A3 + ((wb * 3 + 1) * 64 + slot) * 16) =
        make_uint4(m[0] | (m[1] << 16), m[2] | (m[3] << 16), m[4] | (m[5] << 16), m[6] | (m[7] << 16));
    *(uint4*)((char*)A3 + ((wb * 3 + 2) * 64 + slot) * 16) =
        make_uint4(l[0] | (l[1] << 16), l[2] | (l[3] << 16), l[4] | (l[5] << 16), l[6] | (l[7] << 16));
    const uint4* src = MT3 + (size_t)kit * 3072;
#pragma unroll
    for (int i = 0; i < 12; ++i) {
      int gs = (w * 12 + i) * 64;
      gload_lds16(src + gs + lane, B3 + (size_t)gs * 16);
    }
    __syncthreads();
    bfrag ah = *(const bfrag*)((const char*)A3 + ((w * 3 + 0) * 64 + lane) * 16);
    bfrag am = *(const bfrag*)((const char*)A3 + ((w * 3 + 1) * 64 + lane) * 16);
    bfrag al = *(const bfrag*)((const char*)A3 + ((w * 3 + 2) * 64 + lane) * 16);
#pragma unroll
    for (int nf = 0; nf < 16; ++nf) {
      bfrag bh = *(const bfrag*)(B3 + ((nf * 3 + 0) * 64 + lane) * 16);
      bfrag bm = *(const bfrag*)(B3 + ((nf * 3 + 1) * 64 + lane) * 16);
      bfrag bl = *(const bfrag*)(B3 + ((nf * 3 + 2) * 64 + lane) * 16);
      acc[nf] = __builtin_amdgcn_mfma_f32_16x16x32_bf16(ah, bh, acc[nf], 0, 0, 0);
      acc[nf] = __builtin_amdgcn_mfma_f32_16x16x32_bf16(ah, bm, acc[nf], 0, 0, 0);
      acc[nf] = __builtin_amdgcn_mfma_f32_16x16x32_bf16(am, bh, acc[nf], 0, 0, 0);
      acc[nf] = __builtin_amdgcn_mfma_f32_16x16x32_bf16(ah, bl, acc[nf], 0, 0, 0);
      acc[nf] = __builtin_amdgcn_mfma_f32_16x16x32_bf16(al, bh, acc[nf], 0, 0, 0);
      acc[nf] = __builtin_amdgcn_mfma_f32_16x16x32_bf16(am, bm, acc[nf], 0, 0, 0);
    }
    __syncthreads();
  }
#pragma unroll
  for (int nf = 0; nf < 16; ++nf)
#pragma unroll
    for (int reg = 0; reg < 4; ++reg)
      C[(size_t)(16 * w + l4 * 4 + reg) * 260 + nf * 16 + l15] = acc[nf][reg];
  __syncthreads();
  float part = 0.f;
#pragma unroll
  for (int j = 0; j < 16; ++j) {
    f4 xv = *(const f4*)(xrow + g * 64 + 4 * j);
    f4 cv = *(const f4*)&C[(size_t)r * 260 + g * 64 + 4 * j];
    part = fmaf(xv.x, cv.x, fmaf(xv.y, cv.y, fmaf(xv.z, cv.z, fmaf(xv.w, cv.w, part))));
  }
  part += __shfl_xor(part, 1);
  part += __shfl_xor(part, 2);
  if (g == 0 && row0 + r < NT) Xprod[row0 + r] = part;
}

// ------------- cross v5: pipelined MFMA + per-column running top-5 -------------
// One phase = one (row-pair, kit32). Stage(g+1) issued before compute(g);
// vmcnt(8) counted wait; barriers bracket the LDS-coherent region.
#define CROSS_PHASE(VMLIT)                                                     \
  {                                                                           \
    asm volatile("s_waitcnt vmcnt(" #VMLIT ")" ::: "memory");                 \
    __builtin_amdgcn_s_barrier();                                             \
    asm volatile("" ::: "memory");                                            \
    const char* Ab = Abuf[g & 1];                                             \
    const char* Bb = Bbuf[g & 1];                                             \
    bfrag ah[8], al[8], bh[2], bl[2];                                         \
    _Pragma("unroll")                                                         \
    for (int mf = 0; mf < 8; ++mf) {                                          \
      int m = mf * 16 + l15;                                                  \
      const char* rb = Ab + m * 128;                                          \
      ah[mf] = *(const bfrag*)(rb + ((l4 ^ (m & 7)) << 4));                   \
      al[mf] = *(const bfrag*)(rb + (((l4 + 4) ^ (m & 7)) << 4));             \
    }                                                                         \
    _Pragma("unroll")                                                         \
    for (int nf = 0; nf < 2; ++nf) {                                          \
      int nn = w * 32 + nf * 16 + l15;                                        \
      const char* rb = Bb + nn * 128;                                         \
      bh[nf] = *(const bfrag*)(rb + ((l4 ^ (nn & 7)) << 4));                  \
      bl[nf] = *(const bfrag*)(rb + (((l4 + 4) ^ (nn & 7)) << 4));            \
    }                                                                         \
    __builtin_amdgcn_s_setprio(1);                                            \
    _Pragma("unroll")                                                         \
    for (int mf = 0; mf < 8; ++mf) {                                          \
      acc[mf][0] = __builtin_amdgcn_mfma_f32_16x16x32_bf16(ah[mf], bh[0], acc[mf][0], 0, 0, 0); \
      acc[mf][1] = __builtin_amdgcn_mfma_f32_16x16x32_bf16(ah[mf], bh[1], acc[mf][1], 0, 0, 0); \
    }                                                                         \
    _Pragma("unroll")                                                         \
    for (int mf = 0; mf < 8; ++mf) {                                          \
      acc[mf][0] = __builtin_amdgcn_mfma_f32_16x16x32_bf16(ah[mf], bl[0], acc[mf][0], 0, 0, 0); \
      acc[mf][1] = __builtin_amdgcn_mfma_f32_16x16x32_bf16(ah[mf], bl[1], acc[mf][1], 0, 0, 0); \
    }                                                                         \
    _Pragma("unroll")                                                         \
    for (int mf = 0; mf < 8; ++mf) {                                          \
      acc[mf][0] = __builtin_amdgcn_mfma_f32_16x16x32_bf16(al[mf], bh[0], acc[mf][0], 0, 0, 0); \
      acc[mf][1] = __builtin_amdgcn_mfma_f32_16x16x32_bf16(al[mf], bh[1], acc[mf][1], 0, 0, 0); \
    }                                                                         \
    __builtin_amdgcn_s_setprio(0);                                            \
    if ((g & 7) == 7) {                                                       \
      const int trow0 = row0 + (g >> 3) * 128;                                \
      _Pragma("unroll")                                                       \
      for (int mf = 0; mf < 8; ++mf) {                                        \
        f4 xv = *(const f4*)(Xprod + trow0 + mf * 16 + l4 * 4);               \
        _Pragma("unroll")                                                     \
        for (int rg = 0; rg < 4; ++rg) {                                      \
          int grow = trow0 + mf * 16 + l4 * 4 + rg;                           \
          float xp = (rg == 0) ? xv.x : (rg == 1) ? xv.y : (rg == 2) ? xv.z : xv.w; \
          if (grow < NT) {                                                    \
            float v0 = xp + acc[mf][0][rg];                                   \
            ins5run(bv[0], bi[0], v0, grow);                                  \
            float v1 = xp + acc[mf][1][rg];                                   \
            ins5run(bv[1], bi[1], v1, grow);                                  \
          }                                                                   \
        }                                                                     \
      }                                                                       \
      _Pragma("unroll")                                                       \
      for (int mf = 0; mf < 8; ++mf) {                                        \
        f32x4 z = {0.f, 0.f, 0.f, 0.f};                                       \
        acc[mf][0] = z; acc[mf][1] = z;                                       \
      }                                                                       \
    }                                                                         \
    __builtin_amdgcn_s_barrier();                                             \
    asm volatile("" ::: "memory");                                            \
  }

__global__ __launch_bounds__(256, 2)
void cross_topk_kernel(const uint4* __restrict__ Xsp, const uint4* __restrict__ Z2,
                       const float* __restrict__ Xprod,
                       float* __restrict__ cand_v, int* __restrict__ cand_i,
                       int NT, int NEVAL) {
  __shared__ __align__(16) char Abuf[2][16384];
  __shared__ __align__(16) char Bbuf[2][16384];

  const int t = threadIdx.x;
  const int w = t >> 6, lane = t & 63;
  const int l15 = lane & 15, l4 = lane >> 4;
  // XCD-aware swizzle: same-chunk col-tiles share an XCD's L2
  int n = blockIdx.y * gridDim.x + blockIdx.x;
  int nwg = gridDim.x * gridDim.y;
  int wg = n;
  if ((nwg & 7) == 0) wg = (n & 7) * (nwg >> 3) + (n >> 3);
  const int ct = wg % gridDim.x;
  const int ch = wg / gridDim.x;
  const int c0 = ct * COLS;
  const int row0 = ch * CHUNK;
  const int rows = min(CHUNK, NT - row0);
  const int nrp = (rows + 127) >> 7;
  const int G = nrp * 8;
  const int tile0 = ch * (CHUNK >> 7);

  float bv[2][KNN]; int bi[2][KNN];
#pragma unroll
  for (int nf = 0; nf < 2; ++nf)
#pragma unroll
    for (int s = 0; s < KNN; ++s) { bv[nf][s] = FLT_MAX; bi[nf][s] = 0x7fffffff; }

  f32x4 acc[8][2];
#pragma unroll
  for (int mf = 0; mf < 8; ++mf) {
    f32x4 z = {0.f, 0.f, 0.f, 0.f};
    acc[mf][0] = z; acc[mf][1] = z;
  }

  auto stageA = [&](int gg) {
    const uint4* src = Xsp + ((size_t)(tile0 + (gg >> 3)) * 8 + (gg & 7)) * 1024;
    char* dst = Abuf[gg & 1];
#pragma unroll
    for (int i = 0; i < 4; ++i) {
      int sl = (w * 4 + i) * 64;
      gload_lds16(src + sl + lane, dst + sl * 16);
    }
  };
  auto stageB = [&](int gg) {
    const uint4* src = Z2 + ((size_t)ct * 8 + (gg & 7)) * 1024;
    char* dst = Bbuf[gg & 1];
#pragma unroll
    for (int i = 0; i < 4; ++i) {
      int sl = (w * 4 + i) * 64;
      gload_lds16(src + sl + lane, dst + sl * 16);
    }
  };

  stageA(0); stageB(0);
  int g = 0;
  for (; g < G - 1; ++g) {
    stageA(g + 1);
    stageB(g + 1);
    CROSS_PHASE(8)
  }
  CROSS_PHASE(0)

  // write 4 partial lists per column (keyed by l4 row-group)
#pragma unroll
  for (int nf = 0; nf < 2; ++nf) {
    int col = c0 + w * 32 + nf * 16 + l15;
    size_t o = (((size_t)ch * NEVAL + col) * NSRC + l4) * KNN;
#pragma unroll
    for (int s = 0; s < KNN; ++s) { cand_v[o + s] = bv[nf][s]; cand_i[o + s] = bi[nf][s]; }
  }
}

// ------------- finalize: merge 980 -> top-10 -> exact rescore -> top-5 -------------
__global__ __launch_bounds__(64)
void finalize_kernel(const float* __restrict__ cand_v, const int* __restrict__ cand_i,
                     const float* __restrict__ X, const float* __restrict__ ZTf32,
                     const float* __restrict__ Xprod, const int* __restrict__ y,
                     float* __restrict__ out, int NCH, int NEVAL, int NT) {
  __shared__ float ztl[DD];
  const int j = blockIdx.x;
  const int lane = threadIdx.x;
#pragma unroll
  for (int i = 0; i < 4; ++i) {
    int k = lane + 64 * i;
    ztl[k] = ZTf32[(size_t)k * NEVAL + j];
  }
  __syncthreads();

  float bv[10]; int bi[10];
#pragma unroll
  for (int s = 0; s < 10; ++s) { bv[s] = FLT_MAX; bi[s] = 0x7fffffff; }
  const int NC = NCH * NSRC * KNN;
  for (int p = lane; p < NC; p += 64) {
    int chq = p / 20, u = p - chq * 20;
    size_t o = ((size_t)chq * NEVAL + j) * 20 + u;
    ins10(bv, bi, cand_v[o], cand_i[o]);
  }
#pragma unroll
  for (int st = 0; st < 6; ++st) {
    float pv[10]; int pi[10];
#pragma unroll
    for (int s = 0; s < 10; ++s) {
      pv[s] = __shfl_xor(bv[s], 1 << st);
      pi[s] = __shfl_xor(bi[s], 1 << st);
    }
#pragma unroll
    for (int s = 0; s < 10; ++s) ins10(bv, bi, pv[s], pi[s]);
  }
  float ex[10];
#pragma unroll
  for (int c = 0; c < 10; ++c) {
    int idx = bi[c];
    float part = 0.f;
#pragma unroll
    for (int i = 0; i < 4; ++i) {
      int k = lane + 64 * i;
      part = fmaf(X[(size_t)idx * DD + k], ztl[k], part);
    }
#pragma unroll
    for (int st = 0; st < 6; ++st) part += __shfl_xor(part, 1 << st);
    ex[c] = Xprod[idx] - 2.f * part;
  }
  float fv[KNN]; int fi[KNN];
#pragma unroll
  for (int s = 0; s < KNN; ++s) { fv[s] = FLT_MAX; fi[s] = 0x7fffffff; }
#pragma unroll
  for (int c = 0; c < 10; ++c) ins5lex(fv, fi, ex[c], bi[c]);
  int lb[KNN];
#pragma unroll
  for (int s = 0; s < KNN; ++s) lb[s] = y[fi[s]];
  for (int q = lane; q < NLAB; q += 64) {
    int cnt = (lb[0] == q) + (lb[1] == q) + (lb[2] == q) + (lb[3] == q) + (lb[4] == q);
    out[(size_t)j * NLAB + q] = (float)cnt - (float)q * 0.01f;
  }
}

extern "C" void kernel_launch(void* const* d_in, const int* in_sizes, int n_in,
                              void* d_out, int out_size, void* d_ws, size_t ws_size,
                              hipStream_t stream) {
  const float* X  = (const float*)d_in[0];
  const float* M  = (const float*)d_in[1];
  const float* Xe = (const float*)d_in[2];
  const int*   y  = (const int*)d_in[3];
  const int NT    = in_sizes[0] / DD;          // 100000
  const int NEVAL = in_sizes[2] / DD;          // 2048
  const int NCH   = (NT + CHUNK - 1) / CHUNK;  // 49
  const int NT64  = (NT + 63) / 64;
  const int NT128 = (NT + 127) / 128;          // 782

  char* ws = (char*)d_ws;
  uint4* Z2     = (uint4*)ws;                               // 2 MB
  float* ZTf32  = (float*)(ws + (2 << 20));                 // 2 MB
  uint4* MT3    = (uint4*)(ws + (4 << 20));                 // 384 KB
  float* Xprod  = (float*)(ws + (4 << 20) + (512 << 10));   // NT f32 (+pad to 5MB)
  float* cand_v = (float*)(ws + (5 << 20));                 // 8.03 MB
  int*   cand_i = (int*)((char*)cand_v + (size_t)NCH * NEVAL * NSRC * KNN * 4);
  uint4* Xsp    = (uint4*)(ws + (24ULL << 20));             // 782*128KB = 102.4 MB
  float* out    = (float*)d_out;

  msplit_kernel<<<dim3(32), 256, 0, stream>>>(M, MT3);
  prep_kernel<<<dim3(NEVAL / 64, DD / 64), 256, 0, stream>>>(M, Xe, ZTf32, Z2, NEVAL);
  xsplit_kernel<<<dim3(NT128 * 16), 256, 0, stream>>>(X, Xsp, NT, NT128);
  xprod_kernel<<<dim3(NT64), 256, 0, stream>>>(X, MT3, Xprod, NT);
  cross_topk_kernel<<<dim3(NEVAL / COLS, NCH), 256, 0, stream>>>(
      Xsp, Z2, Xprod, cand_v, cand_i, NT, NEVAL);
  finalize_kernel<<<dim3(NEVAL), 64, 0, stream>>>(
      cand_v, cand_i, X, ZTf32, Xprod, y, out, NCH, NEVAL, NT);
}